// Round 1
// baseline (1655.678 us; speedup 1.0000x reference)
//
#include <hip/hip_runtime.h>
#include <hip/hip_bf16.h>

// Problem constants (match reference)
#define NN 100000      // nodes
#define FE 512         // in_feats
#define HF 128         // h_feats
#define NE 1600000     // edges
#define NNIE 4         // hops+1

// ---------------------------------------------------------------------------
// Graph preprocessing kernels
// ---------------------------------------------------------------------------
__global__ __launch_bounds__(256) void k_zero(int* __restrict__ deg,
                                              int* __restrict__ cursor, int n) {
    int i = blockIdx.x * 256 + threadIdx.x;
    if (i < n) { deg[i] = 0; cursor[i] = 0; }
}

__global__ __launch_bounds__(256) void k_count(const int* __restrict__ row,
                                               int* __restrict__ deg, int e) {
    int i = blockIdx.x * 256 + threadIdx.x;
    if (i < e) atomicAdd(&deg[row[i]], 1);
}

__global__ __launch_bounds__(256) void k_dinv(const int* __restrict__ deg,
                                              float* __restrict__ dinv, int n) {
    int i = blockIdx.x * 256 + threadIdx.x;
    if (i < n) dinv[i] = 1.0f / sqrtf((float)(deg[i] + 1));  // +1 self loop
}

// single-block exclusive scan of counts -> offsets (n = 100000, trivial time)
__global__ __launch_bounds__(1024) void k_scan(const int* __restrict__ cnt,
                                               int* __restrict__ off, int n) {
    __shared__ int sm[1024];
    __shared__ int carry_s;
    int tid = threadIdx.x;
    if (tid == 0) carry_s = 0;
    __syncthreads();
    for (int base = 0; base < n; base += 1024) {
        int v = (base + tid < n) ? cnt[base + tid] : 0;
        sm[tid] = v;
        __syncthreads();
        for (int s = 1; s < 1024; s <<= 1) {
            int t = (tid >= s) ? sm[tid - s] : 0;
            __syncthreads();
            sm[tid] += t;
            __syncthreads();
        }
        int c = carry_s;
        if (base + tid < n) off[base + tid] = c + sm[tid] - v;  // exclusive
        __syncthreads();
        if (tid == 1023) carry_s = c + sm[1023];
        __syncthreads();
    }
    if (tid == 0) off[n] = carry_s;
}

__global__ __launch_bounds__(256) void k_fill(const int* __restrict__ rows,
                                              const int* __restrict__ cols,
                                              const float* __restrict__ dinv,
                                              const int* __restrict__ off,
                                              int* __restrict__ cursor,
                                              int* __restrict__ col_s,
                                              float* __restrict__ w_s, int e) {
    int i = blockIdx.x * 256 + threadIdx.x;
    if (i < e) {
        int r = rows[i], c = cols[i];
        int pos = off[r] + atomicAdd(&cursor[r], 1);
        col_s[pos] = c;
        w_s[pos] = dinv[r] * dinv[c];
    }
}

// ---------------------------------------------------------------------------
// SpMM: y[i] = dinv[i]^2 * z[i] + sum_{e in CSR[i]} w_e * z[col_e]
// one wave per node; lane handles float2 (128 floats / 64 lanes)
// ---------------------------------------------------------------------------
__global__ __launch_bounds__(256) void k_spmm(const float* __restrict__ z,
                                              float* __restrict__ y,
                                              const int* __restrict__ off,
                                              const int* __restrict__ cols,
                                              const float* __restrict__ w,
                                              const float* __restrict__ dinv,
                                              int n) {
    int node = blockIdx.x * 4 + (threadIdx.x >> 6);
    int lane = threadIdx.x & 63;
    if (node >= n) return;
    const float2* zr = (const float2*)z;
    float di = dinv[node];
    float2 v = zr[(size_t)node * 64 + lane];
    float2 acc;
    acc.x = di * di * v.x;
    acc.y = di * di * v.y;
    int p1 = off[node + 1];
    for (int p = off[node]; p < p1; ++p) {
        int c = cols[p];
        float ww = w[p];
        float2 t = zr[(size_t)c * 64 + lane];
        acc.x = fmaf(ww, t.x, acc.x);
        acc.y = fmaf(ww, t.y, acc.y);
    }
    ((float2*)y)[(size_t)node * 64 + lane] = acc;
}

// ---------------------------------------------------------------------------
// Fused GEMM (M x K @ K x 128) + optional row-L2-normalize of A (applied in
// epilogue: y = rn*(x.W)+b) + bias + LayerNorm + ReLU.
// Block: 256 threads, BM=64 rows x BN=128 cols, BK=16.
// Thread (ty=tid/32, tx=tid%32): rows ty*8..ty*8+7, cols 4tx..4tx+3.
// Each row's 32 owner threads are a contiguous half-wave -> shfl LN reduce.
// ---------------------------------------------------------------------------
template <int K, bool NORM>
__global__ __launch_bounds__(256) void gemm_ln(
    const float* __restrict__ A, int lda, const float* __restrict__ W,
    const float* __restrict__ bias, const float* __restrict__ g,
    const float* __restrict__ be, float* __restrict__ out, int ldo, int M) {
    constexpr int BM = 64, BK = 16;
    __shared__ float Ast[BK][BM + 4];    // transposed A tile [k][row]
    __shared__ float Bs[BK][128 + 4];
    __shared__ float rn_s[BM];

    const int tid = threadIdx.x;
    const int row0 = blockIdx.x * BM;
    const int tx = tid & 31;
    const int ty = tid >> 5;
    const int lrow = tid >> 2;  // A-loader: row 0..63
    const int lq = tid & 3;     // A-loader: k quad 0..3

    float acc[8][4];
#pragma unroll
    for (int i = 0; i < 8; i++)
#pragma unroll
        for (int j = 0; j < 4; j++) acc[i][j] = 0.0f;

    float sumsq = 0.0f;
    const bool arow_ok = (row0 + lrow) < M;
    const float* Aptr = A + (size_t)(row0 + lrow) * lda + 4 * lq;
    const int kb = tid >> 5;

    for (int k0 = 0; k0 < K; k0 += BK) {
        float4 av = make_float4(0.f, 0.f, 0.f, 0.f);
        if (arow_ok) av = *(const float4*)(Aptr + k0);
        if (NORM)
            sumsq += av.x * av.x + av.y * av.y + av.z * av.z + av.w * av.w;
        Ast[4 * lq + 0][lrow] = av.x;
        Ast[4 * lq + 1][lrow] = av.y;
        Ast[4 * lq + 2][lrow] = av.z;
        Ast[4 * lq + 3][lrow] = av.w;
        float4 b0 = *(const float4*)(W + (size_t)(k0 + kb) * 128 + 4 * tx);
        float4 b1 = *(const float4*)(W + (size_t)(k0 + kb + 8) * 128 + 4 * tx);
        *(float4*)&Bs[kb][4 * tx] = b0;
        *(float4*)&Bs[kb + 8][4 * tx] = b1;
        __syncthreads();
#pragma unroll
        for (int kk = 0; kk < BK; ++kk) {
            float4 a0 = *(const float4*)&Ast[kk][ty * 8];
            float4 a1 = *(const float4*)&Ast[kk][ty * 8 + 4];
            float4 bv = *(const float4*)&Bs[kk][4 * tx];
            float ar[8] = {a0.x, a0.y, a0.z, a0.w, a1.x, a1.y, a1.z, a1.w};
            float bc[4] = {bv.x, bv.y, bv.z, bv.w};
#pragma unroll
            for (int i = 0; i < 8; i++)
#pragma unroll
                for (int j = 0; j < 4; j++)
                    acc[i][j] = fmaf(ar[i], bc[j], acc[i][j]);
        }
        __syncthreads();
    }

    if (NORM) {
        // reduce sumsq over the 4 consecutive lanes sharing lrow
        sumsq += __shfl_xor(sumsq, 1);
        sumsq += __shfl_xor(sumsq, 2);
        if (lq == 0) rn_s[lrow] = 1.0f / fmaxf(sqrtf(sumsq), 1e-12f);
    }
    __syncthreads();

    float bb[4], gg[4], ee[4];
    {
        const float4 b4 = *(const float4*)(bias + 4 * tx);
        const float4 g4 = *(const float4*)(g + 4 * tx);
        const float4 e4 = *(const float4*)(be + 4 * tx);
        bb[0] = b4.x; bb[1] = b4.y; bb[2] = b4.z; bb[3] = b4.w;
        gg[0] = g4.x; gg[1] = g4.y; gg[2] = g4.z; gg[3] = g4.w;
        ee[0] = e4.x; ee[1] = e4.y; ee[2] = e4.z; ee[3] = e4.w;
    }

#pragma unroll
    for (int i = 0; i < 8; i++) {
        const int row = ty * 8 + i;
        float rn = 1.0f;
        if (NORM) rn = rn_s[row];
        float y[4], s1 = 0.0f, s2 = 0.0f;
#pragma unroll
        for (int j = 0; j < 4; j++) {
            y[j] = fmaf(acc[i][j], rn, bb[j]);
            s1 += y[j];
            s2 = fmaf(y[j], y[j], s2);
        }
#pragma unroll
        for (int m = 1; m <= 16; m <<= 1) {
            s1 += __shfl_xor(s1, m);
            s2 += __shfl_xor(s2, m);
        }
        const float mean = s1 * (1.0f / 128.0f);
        const float var = fmaxf(s2 * (1.0f / 128.0f) - mean * mean, 0.0f);
        const float rstd = rsqrtf(var + 1e-5f);
        float4 o;
        o.x = fmaxf(fmaf((y[0] - mean) * rstd, gg[0], ee[0]), 0.0f);
        o.y = fmaxf(fmaf((y[1] - mean) * rstd, gg[1], ee[1]), 0.0f);
        o.z = fmaxf(fmaf((y[2] - mean) * rstd, gg[2], ee[2]), 0.0f);
        o.w = fmaxf(fmaf((y[3] - mean) * rstd, gg[3], ee[3]), 0.0f);
        if (row0 + row < M)
            *(float4*)(out + (size_t)(row0 + row) * ldo + 4 * tx) = o;
    }
}

// ---------------------------------------------------------------------------
extern "C" void kernel_launch(void* const* d_in, const int* in_sizes, int n_in,
                              void* d_out, int out_size, void* d_ws,
                              size_t ws_size, hipStream_t stream) {
    const int* ei = (const int*)d_in[0];          // [2, E]
    const float* feats = (const float*)d_in[1];   // [N, 512]
    const float* W_uni = (const float*)d_in[2];   // [512,128]
    const float* b_uni = (const float*)d_in[3];
    const float* g_uni = (const float*)d_in[4];
    const float* be_uni = (const float*)d_in[5];
    const float* W_ind = (const float*)d_in[6];   // [4,128,128]
    const float* b_ind = (const float*)d_in[7];   // [4,128]
    const float* g_ind = (const float*)d_in[8];
    const float* be_ind = (const float*)d_in[9];
    const float* W_rel = (const float*)d_in[10];  // [512,128]
    const float* b_rel = (const float*)d_in[11];
    const float* g_rel = (const float*)d_in[12];
    const float* be_rel = (const float*)d_in[13];
    float* out = (float*)d_out;

    // workspace carve (all re-derived every call; ws is poisoned)
    char* p = (char*)d_ws;
    auto alloc = [&](size_t bytes) {
        void* r = (void*)p;
        p += (bytes + 255) & ~(size_t)255;
        return r;
    };
    int* deg = (int*)alloc(NN * 4);
    int* cursor = (int*)alloc(NN * 4);
    int* off = (int*)alloc((NN + 1) * 4);
    int* col_s = (int*)alloc((size_t)NE * 4);
    float* w_s = (float*)alloc((size_t)NE * 4);
    float* dinv = (float*)alloc(NN * 4);
    float* h = (float*)alloc((size_t)NN * HF * 4);
    float* za = (float*)alloc((size_t)NN * HF * 4);
    float* zb = (float*)alloc((size_t)NN * HF * 4);
    float* cat = (float*)alloc((size_t)NN * (NNIE * HF) * 4);

    const int gE = (NE + 255) / 256;
    const int gN = (NN + 255) / 256;
    const int gGemm = (NN + 63) / 64;
    const int gSpmm = (NN + 3) / 4;
    const int* erow = ei;       // edge_index[0]
    const int* ecol = ei + NE;  // edge_index[1]

    // graph prep
    k_zero<<<gN, 256, 0, stream>>>(deg, cursor, NN);
    k_count<<<gE, 256, 0, stream>>>(erow, deg, NE);
    k_dinv<<<gN, 256, 0, stream>>>(deg, dinv, NN);
    k_scan<<<1, 1024, 0, stream>>>(deg, off, NN);
    k_fill<<<gE, 256, 0, stream>>>(erow, ecol, dinv, off, cursor, col_s, w_s,
                                   NE);

    // unified transform: h = relu(LN(normalize(x) @ W_uni + b))
    gemm_ln<FE, true><<<gGemm, 256, 0, stream>>>(feats, FE, W_uni, b_uni,
                                                 g_uni, be_uni, h, HF, NN);

    // hop 0
    gemm_ln<HF, false><<<gGemm, 256, 0, stream>>>(
        h, HF, W_ind + 0 * HF * HF, b_ind + 0 * HF, g_ind + 0 * HF,
        be_ind + 0 * HF, cat + 0 * HF, NNIE * HF, NN);
    // hop 1
    k_spmm<<<gSpmm, 256, 0, stream>>>(h, za, off, col_s, w_s, dinv, NN);
    gemm_ln<HF, false><<<gGemm, 256, 0, stream>>>(
        za, HF, W_ind + 1 * HF * HF, b_ind + 1 * HF, g_ind + 1 * HF,
        be_ind + 1 * HF, cat + 1 * HF, NNIE * HF, NN);
    // hop 2
    k_spmm<<<gSpmm, 256, 0, stream>>>(za, zb, off, col_s, w_s, dinv, NN);
    gemm_ln<HF, false><<<gGemm, 256, 0, stream>>>(
        zb, HF, W_ind + 2 * HF * HF, b_ind + 2 * HF, g_ind + 2 * HF,
        be_ind + 2 * HF, cat + 2 * HF, NNIE * HF, NN);
    // hop 3
    k_spmm<<<gSpmm, 256, 0, stream>>>(zb, za, off, col_s, w_s, dinv, NN);
    gemm_ln<HF, false><<<gGemm, 256, 0, stream>>>(
        za, HF, W_ind + 3 * HF * HF, b_ind + 3 * HF, g_ind + 3 * HF,
        be_ind + 3 * HF, cat + 3 * HF, NNIE * HF, NN);

    // relation network: out = relu(LN(cat @ W_rel + b))
    gemm_ln<NNIE * HF, false><<<gGemm, 256, 0, stream>>>(
        cat, NNIE * HF, W_rel, b_rel, g_rel, be_rel, out, HF, NN);
}

// Round 2
// 1181.642 us; speedup vs baseline: 1.4012x; 1.4012x over previous
//
#include <hip/hip_runtime.h>
#include <hip/hip_bf16.h>

// Problem constants (match reference)
#define NN 100000      // nodes
#define FE 512         // in_feats
#define HF 128         // h_feats
#define NE 1600000     // edges
#define NNIE 4         // hops+1

typedef __attribute__((ext_vector_type(8))) __bf16 bf16x8;
typedef __attribute__((ext_vector_type(4))) float f32x4;
typedef __attribute__((ext_vector_type(8))) unsigned short ushort8;

__device__ __forceinline__ unsigned short f2bf(float f) {
    unsigned u = __float_as_uint(f);
    unsigned r = (u + 0x7fffu + ((u >> 16) & 1u)) >> 16;  // RNE
    return (unsigned short)r;
}
__device__ __forceinline__ float b2f(unsigned short u) {
    return __uint_as_float(((unsigned)u) << 16);
}

// ---------------------------------------------------------------------------
// Graph preprocessing
// ---------------------------------------------------------------------------
__global__ __launch_bounds__(256) void k_zero(int* __restrict__ deg,
                                              int* __restrict__ cursor, int n) {
    int i = blockIdx.x * 256 + threadIdx.x;
    if (i < n) { deg[i] = 0; cursor[i] = 0; }
}

__global__ __launch_bounds__(256) void k_count(const int* __restrict__ row,
                                               int* __restrict__ deg, int e) {
    int i = blockIdx.x * 256 + threadIdx.x;
    if (i < e) atomicAdd(&deg[row[i]], 1);
}

__global__ __launch_bounds__(256) void k_dinv(const int* __restrict__ deg,
                                              float* __restrict__ dinv, int n) {
    int i = blockIdx.x * 256 + threadIdx.x;
    if (i < n) dinv[i] = 1.0f / sqrtf((float)(deg[i] + 1));  // +1 self loop
}

// shuffle-based exclusive scan (single block, 1024 threads)
__global__ __launch_bounds__(1024) void k_scan(const int* __restrict__ cnt,
                                               int* __restrict__ off, int n) {
    __shared__ int wsum[16];
    __shared__ int carry_s;
    const int tid = threadIdx.x, lane = tid & 63, wid = tid >> 6;
    if (tid == 0) carry_s = 0;
    __syncthreads();
    for (int base = 0; base < n; base += 1024) {
        int v = (base + tid < n) ? cnt[base + tid] : 0;
        int x = v;  // inclusive scan within wave
#pragma unroll
        for (int s = 1; s < 64; s <<= 1) {
            int t = __shfl_up(x, s);
            if (lane >= s) x += t;
        }
        if (lane == 63) wsum[wid] = x;
        __syncthreads();
        if (wid == 0 && lane < 16) {
            int t = wsum[lane];
#pragma unroll
            for (int s = 1; s < 16; s <<= 1) {
                int u = __shfl_up(t, s);
                if (lane >= s) t += u;
            }
            wsum[lane] = t;  // inclusive wave-sum scan
        }
        __syncthreads();
        const int wexc = (wid == 0) ? 0 : wsum[wid - 1];
        const int c = carry_s;
        if (base + tid < n) off[base + tid] = c + wexc + x - v;  // exclusive
        __syncthreads();
        if (tid == 1023) carry_s = c + wsum[15];
        __syncthreads();
    }
    if (threadIdx.x == 0) off[n] = carry_s;
}

__global__ __launch_bounds__(256) void k_fill(const int* __restrict__ rows,
                                              const int* __restrict__ cols,
                                              const float* __restrict__ dinv,
                                              const int* __restrict__ off,
                                              int* __restrict__ cursor,
                                              int* __restrict__ col_s,
                                              float* __restrict__ w_s, int e) {
    int i = blockIdx.x * 256 + threadIdx.x;
    if (i < e) {
        int r = rows[i], c = cols[i];
        int pos = off[r] + atomicAdd(&cursor[r], 1);
        col_s[pos] = c;
        w_s[pos] = dinv[r] * dinv[c];
    }
}

// weight convert+transpose: W [K][128] fp32 -> Wt [128][K] bf16
__global__ __launch_bounds__(256) void k_wt(const float* __restrict__ W,
                                            unsigned short* __restrict__ Wt,
                                            int K) {
    int i = blockIdx.x * 256 + threadIdx.x;
    if (i < K * 128) {
        int k = i >> 7, n = i & 127;
        Wt[n * K + k] = f2bf(W[i]);
    }
}

// ---------------------------------------------------------------------------
// SpMM (bf16): y[i] = dinv[i]^2*z[i] + sum_e w_e * z[col_e]
// one wave per node; lane handles bf16x2 (128 feats / 64 lanes)
// ---------------------------------------------------------------------------
__global__ __launch_bounds__(256) void k_spmm(
    const unsigned short* __restrict__ z, unsigned short* __restrict__ y,
    const int* __restrict__ off, const int* __restrict__ cols,
    const float* __restrict__ w, const float* __restrict__ dinv, int n) {
    int node = blockIdx.x * 4 + (threadIdx.x >> 6);
    int lane = threadIdx.x & 63;
    if (node >= n) return;
    const unsigned* zr = (const unsigned*)z;  // bf16x2 words
    float di = dinv[node];
    unsigned v = zr[(size_t)node * 64 + lane];
    float ax = di * di * b2f((unsigned short)(v & 0xffff));
    float ay = di * di * b2f((unsigned short)(v >> 16));
    const int p1 = off[node + 1];
    for (int p = off[node]; p < p1; ++p) {
        int c = cols[p];
        float ww = w[p];
        unsigned t = zr[(size_t)c * 64 + lane];
        ax = fmaf(ww, b2f((unsigned short)(t & 0xffff)), ax);
        ay = fmaf(ww, b2f((unsigned short)(t >> 16)), ay);
    }
    ((unsigned*)y)[(size_t)node * 64 + lane] =
        (unsigned)f2bf(ax) | ((unsigned)f2bf(ay) << 16);
}

// ---------------------------------------------------------------------------
// MFMA GEMM (M x K @ K x 128) + optional row-L2-normalize of A (epilogue
// scale) + bias + LayerNorm + ReLU.  A: fp32 or bf16; out: fp32 or bf16.
// Block 256 = 4 waves. BM=64 (wave w: rows 16w..16w+15), BN=128, BK=32.
// mfma_f32_16x16x32_bf16; A-frag A[m=lane&15][k=(lane>>4)*8+j];
// B-frag from Wt[128][K] (B^T) same layout; C/D col=lane&15,row=(lane>>4)*4+r.
// ---------------------------------------------------------------------------
template <int K, bool NORM, typename AT, typename OT>
__global__ __launch_bounds__(256) void gemm_mfma(
    const AT* __restrict__ A, int lda, const unsigned short* __restrict__ Wt,
    const float* __restrict__ bias, const float* __restrict__ g,
    const float* __restrict__ be, OT* __restrict__ out, int ldo, int M) {
    constexpr int LDT = 40;  // row stride in shorts (32 + 8 pad, 16B aligned)
    __shared__ unsigned short Ast[64][LDT];
    __shared__ unsigned short Bst[128][LDT];
    __shared__ float rn_s[64];

    const int tid = threadIdx.x;
    const int row0 = blockIdx.x * 64;
    const int w = tid >> 6;
    const int lane = tid & 63;
    const int m = lane & 15;
    const int q = lane >> 4;
    const int lrow = tid >> 2;  // stager row 0..63
    const int lq = tid & 3;     // stager k-octet

    f32x4 acc[8];
#pragma unroll
    for (int t = 0; t < 8; t++) acc[t] = (f32x4){0.f, 0.f, 0.f, 0.f};

    float sumsq = 0.0f;
    const bool arow_ok = (row0 + lrow) < M;

    for (int k0 = 0; k0 < K; k0 += 32) {
        __syncthreads();
        // ---- stage A tile (64 x 32) -> bf16 LDS
        ushort8 pk;
        if constexpr (sizeof(AT) == 4) {  // fp32 A with on-the-fly cvt
            f32x4 a0 = (f32x4){0.f, 0.f, 0.f, 0.f}, a1 = a0;
            if (arow_ok) {
                const float* Ap =
                    (const float*)A + (size_t)(row0 + lrow) * lda + k0 + 8 * lq;
                a0 = *(const f32x4*)Ap;
                a1 = *(const f32x4*)(Ap + 4);
            }
            if (NORM) {
#pragma unroll
                for (int j = 0; j < 4; j++)
                    sumsq += a0[j] * a0[j] + a1[j] * a1[j];
            }
#pragma unroll
            for (int j = 0; j < 4; j++) {
                pk[j] = f2bf(a0[j]);
                pk[j + 4] = f2bf(a1[j]);
            }
        } else {  // bf16 A
            pk = (ushort8){0, 0, 0, 0, 0, 0, 0, 0};
            if (arow_ok)
                pk = *(const ushort8*)((const unsigned short*)A +
                                       (size_t)(row0 + lrow) * lda + k0 +
                                       8 * lq);
        }
        *(ushort8*)&Ast[lrow][8 * lq] = pk;
        // ---- stage B tile (128 x 32) from Wt[128][K]
#pragma unroll
        for (int j = 0; j < 2; j++) {
            int c = tid + 256 * j;       // 512 chunks of 16B
            int n = c >> 2, qq = c & 3;
            ushort8 bchunk =
                *(const ushort8*)(Wt + (size_t)n * K + k0 + 8 * qq);
            *(ushort8*)&Bst[n][8 * qq] = bchunk;
        }
        __syncthreads();
        // ---- compute: 8 n-tiles per wave
        bf16x8 af = *(const bf16x8*)&Ast[16 * w + m][8 * q];
#pragma unroll
        for (int t = 0; t < 8; t++) {
            bf16x8 bf = *(const bf16x8*)&Bst[16 * t + m][8 * q];
            acc[t] = __builtin_amdgcn_mfma_f32_16x16x32_bf16(af, bf, acc[t], 0,
                                                             0, 0);
        }
    }

    if (NORM) {
        sumsq += __shfl_xor(sumsq, 1);
        sumsq += __shfl_xor(sumsq, 2);
        if (lq == 0) rn_s[lrow] = 1.0f / fmaxf(sqrtf(sumsq), 1e-12f);
        __syncthreads();
    }

    // ---- epilogue: bias + LN + ReLU
    float bb[8], gg[8], ee[8];
#pragma unroll
    for (int t = 0; t < 8; t++) {
        bb[t] = bias[16 * t + m];
        gg[t] = g[16 * t + m];
        ee[t] = be[16 * t + m];
    }
#pragma unroll
    for (int r = 0; r < 4; r++) {
        const int lrow2 = 16 * w + 4 * q + r;  // block-local row
        float rn = 1.0f;
        if (NORM) rn = rn_s[lrow2];
        float s1 = 0.f, s2 = 0.f;
#pragma unroll
        for (int t = 0; t < 8; t++) {
            float y = fmaf(acc[t][r], rn, bb[t]);
            s1 += y;
            s2 = fmaf(y, y, s2);
        }
#pragma unroll
        for (int mask = 1; mask <= 8; mask <<= 1) {
            s1 += __shfl_xor(s1, mask);
            s2 += __shfl_xor(s2, mask);
        }
        const float mean = s1 * (1.0f / 128.0f);
        const float var = fmaxf(s2 * (1.0f / 128.0f) - mean * mean, 0.0f);
        const float rstd = rsqrtf(var + 1e-5f);
        const int grow = row0 + lrow2;
        if (grow < M) {
#pragma unroll
            for (int t = 0; t < 8; t++) {
                float y = fmaf(acc[t][r], rn, bb[t]);
                float o = fmaxf(fmaf((y - mean) * rstd, gg[t], ee[t]), 0.0f);
                if constexpr (sizeof(OT) == 2)
                    ((unsigned short*)out)[(size_t)grow * ldo + 16 * t + m] =
                        f2bf(o);
                else
                    ((float*)out)[(size_t)grow * ldo + 16 * t + m] = o;
            }
        }
    }
}

// ---------------------------------------------------------------------------
extern "C" void kernel_launch(void* const* d_in, const int* in_sizes, int n_in,
                              void* d_out, int out_size, void* d_ws,
                              size_t ws_size, hipStream_t stream) {
    const int* ei = (const int*)d_in[0];          // [2, E]
    const float* feats = (const float*)d_in[1];   // [N, 512]
    const float* W_uni = (const float*)d_in[2];   // [512,128]
    const float* b_uni = (const float*)d_in[3];
    const float* g_uni = (const float*)d_in[4];
    const float* be_uni = (const float*)d_in[5];
    const float* W_ind = (const float*)d_in[6];   // [4,128,128]
    const float* b_ind = (const float*)d_in[7];   // [4,128]
    const float* g_ind = (const float*)d_in[8];
    const float* be_ind = (const float*)d_in[9];
    const float* W_rel = (const float*)d_in[10];  // [512,128]
    const float* b_rel = (const float*)d_in[11];
    const float* g_rel = (const float*)d_in[12];
    const float* be_rel = (const float*)d_in[13];
    float* out = (float*)d_out;

    char* p = (char*)d_ws;
    auto alloc = [&](size_t bytes) {
        void* r = (void*)p;
        p += (bytes + 255) & ~(size_t)255;
        return r;
    };
    int* deg = (int*)alloc(NN * 4);
    int* cursor = (int*)alloc(NN * 4);
    int* off = (int*)alloc((NN + 1) * 4);
    int* col_s = (int*)alloc((size_t)NE * 4);
    float* w_s = (float*)alloc((size_t)NE * 4);
    float* dinv = (float*)alloc(NN * 4);
    unsigned short* Wt_uni = (unsigned short*)alloc(128 * FE * 2);
    unsigned short* Wt_rel = (unsigned short*)alloc(128 * (NNIE * HF) * 2);
    unsigned short* Wt_ind = (unsigned short*)alloc(NNIE * HF * HF * 2);
    unsigned short* h = (unsigned short*)alloc((size_t)NN * HF * 2);
    unsigned short* za = (unsigned short*)alloc((size_t)NN * HF * 2);
    unsigned short* zb = (unsigned short*)alloc((size_t)NN * HF * 2);
    unsigned short* cat = (unsigned short*)alloc((size_t)NN * NNIE * HF * 2);

    const int gE = (NE + 255) / 256;
    const int gN = (NN + 255) / 256;
    const int gGemm = (NN + 63) / 64;
    const int gSpmm = (NN + 3) / 4;
    const int* erow = ei;
    const int* ecol = ei + NE;

    // graph prep
    k_zero<<<gN, 256, 0, stream>>>(deg, cursor, NN);
    k_count<<<gE, 256, 0, stream>>>(erow, deg, NE);
    k_dinv<<<gN, 256, 0, stream>>>(deg, dinv, NN);
    k_scan<<<1, 1024, 0, stream>>>(deg, off, NN);
    k_fill<<<gE, 256, 0, stream>>>(erow, ecol, dinv, off, cursor, col_s, w_s,
                                   NE);

    // weight transpose+cvt (tiny)
    k_wt<<<(FE * 128 + 255) / 256, 256, 0, stream>>>(W_uni, Wt_uni, FE);
    k_wt<<<(NNIE * HF * 128 + 255) / 256, 256, 0, stream>>>(W_rel, Wt_rel,
                                                            NNIE * HF);
    for (int hh = 0; hh < NNIE; hh++)
        k_wt<<<(HF * 128 + 255) / 256, 256, 0, stream>>>(
            W_ind + hh * HF * HF, Wt_ind + hh * HF * HF, HF);

    // unified transform: h = relu(LN(normalize(x) @ W_uni + b))
    gemm_mfma<FE, true, float, unsigned short>
        <<<gGemm, 256, 0, stream>>>(feats, FE, Wt_uni, b_uni, g_uni, be_uni, h,
                                    HF, NN);
    // hop 0
    gemm_mfma<HF, false, unsigned short, unsigned short>
        <<<gGemm, 256, 0, stream>>>(h, HF, Wt_ind + 0 * HF * HF, b_ind, g_ind,
                                    be_ind, cat + 0 * HF, NNIE * HF, NN);
    // hop 1
    k_spmm<<<gSpmm, 256, 0, stream>>>(h, za, off, col_s, w_s, dinv, NN);
    gemm_mfma<HF, false, unsigned short, unsigned short>
        <<<gGemm, 256, 0, stream>>>(za, HF, Wt_ind + 1 * HF * HF, b_ind + HF,
                                    g_ind + HF, be_ind + HF, cat + 1 * HF,
                                    NNIE * HF, NN);
    // hop 2
    k_spmm<<<gSpmm, 256, 0, stream>>>(za, zb, off, col_s, w_s, dinv, NN);
    gemm_mfma<HF, false, unsigned short, unsigned short>
        <<<gGemm, 256, 0, stream>>>(zb, HF, Wt_ind + 2 * HF * HF,
                                    b_ind + 2 * HF, g_ind + 2 * HF,
                                    be_ind + 2 * HF, cat + 2 * HF, NNIE * HF,
                                    NN);
    // hop 3
    k_spmm<<<gSpmm, 256, 0, stream>>>(zb, za, off, col_s, w_s, dinv, NN);
    gemm_mfma<HF, false, unsigned short, unsigned short>
        <<<gGemm, 256, 0, stream>>>(za, HF, Wt_ind + 3 * HF * HF,
                                    b_ind + 3 * HF, g_ind + 3 * HF,
                                    be_ind + 3 * HF, cat + 3 * HF, NNIE * HF,
                                    NN);
    // relation network
    gemm_mfma<NNIE * HF, false, unsigned short, float>
        <<<gGemm, 256, 0, stream>>>(cat, NNIE * HF, Wt_rel, b_rel, g_rel,
                                    be_rel, out, HF, NN);
}

// Round 3
// 822.534 us; speedup vs baseline: 2.0129x; 1.4366x over previous
//
#include <hip/hip_runtime.h>
#include <hip/hip_bf16.h>

// Problem constants (match reference)
#define NN 100000      // nodes
#define FE 512         // in_feats
#define HF 128         // h_feats
#define NE 1600000     // edges
#define NNIE 4         // hops+1

typedef __attribute__((ext_vector_type(8))) __bf16 bf16x8;
typedef __attribute__((ext_vector_type(4))) float f32x4;
typedef __attribute__((ext_vector_type(8))) unsigned short ushort8;

__device__ __forceinline__ unsigned short f2bf(float f) {
    unsigned u = __float_as_uint(f);
    unsigned r = (u + 0x7fffu + ((u >> 16) & 1u)) >> 16;  // RNE
    return (unsigned short)r;
}
__device__ __forceinline__ float b2f(unsigned short u) {
    return __uint_as_float(((unsigned)u) << 16);
}

// ---------------------------------------------------------------------------
// Graph preprocessing
// ---------------------------------------------------------------------------
__global__ __launch_bounds__(256) void k_zero(int* __restrict__ deg,
                                              int* __restrict__ cursor, int n) {
    int i = blockIdx.x * 256 + threadIdx.x;
    if (i < n) { deg[i] = 0; cursor[i] = 0; }
}

__global__ __launch_bounds__(256) void k_count(const int* __restrict__ row,
                                               int* __restrict__ deg, int e) {
    int i = blockIdx.x * 256 + threadIdx.x;
    if (i < e) atomicAdd(&deg[row[i]], 1);
}

__global__ __launch_bounds__(256) void k_dinv(const int* __restrict__ deg,
                                              float* __restrict__ dinv, int n) {
    int i = blockIdx.x * 256 + threadIdx.x;
    if (i < n) dinv[i] = 1.0f / sqrtf((float)(deg[i] + 1));  // +1 self loop
}

// ---- multi-block exclusive scan (3 passes) --------------------------------
// pass 1: per-block (1024) local exclusive scan + block totals
__global__ __launch_bounds__(1024) void k_scan1(const int* __restrict__ cnt,
                                                int* __restrict__ off,
                                                int* __restrict__ bsum, int n) {
    __shared__ int wsum[16];
    const int tid = threadIdx.x, lane = tid & 63, wid = tid >> 6;
    const int i = blockIdx.x * 1024 + tid;
    const int v = (i < n) ? cnt[i] : 0;
    int x = v;
#pragma unroll
    for (int s = 1; s < 64; s <<= 1) {
        int t = __shfl_up(x, s);
        if (lane >= s) x += t;
    }
    if (lane == 63) wsum[wid] = x;
    __syncthreads();
    if (wid == 0 && lane < 16) {
        int t = wsum[lane];
#pragma unroll
        for (int s = 1; s < 16; s <<= 1) {
            int u = __shfl_up(t, s);
            if (lane >= s) t += u;
        }
        wsum[lane] = t;
    }
    __syncthreads();
    const int wexc = (wid == 0) ? 0 : wsum[wid - 1];
    if (i < n) off[i] = wexc + x - v;  // block-local exclusive
    if (tid == 0) bsum[blockIdx.x] = wsum[15];
}
// pass 2: single block scans block totals (nb <= 1024); writes grand total
__global__ __launch_bounds__(1024) void k_scan2(int* __restrict__ bsum, int nb,
                                                int* __restrict__ total_out) {
    __shared__ int wsum[16];
    const int tid = threadIdx.x, lane = tid & 63, wid = tid >> 6;
    const int v = (tid < nb) ? bsum[tid] : 0;
    int x = v;
#pragma unroll
    for (int s = 1; s < 64; s <<= 1) {
        int t = __shfl_up(x, s);
        if (lane >= s) x += t;
    }
    if (lane == 63) wsum[wid] = x;
    __syncthreads();
    if (wid == 0 && lane < 16) {
        int t = wsum[lane];
#pragma unroll
        for (int s = 1; s < 16; s <<= 1) {
            int u = __shfl_up(t, s);
            if (lane >= s) t += u;
        }
        wsum[lane] = t;
    }
    __syncthreads();
    const int wexc = (wid == 0) ? 0 : wsum[wid - 1];
    if (tid < nb) bsum[tid] = wexc + x - v;  // exclusive block offsets
    if (tid == 0) *total_out = wsum[15];
}
// pass 3: add block offsets back
__global__ __launch_bounds__(256) void k_scan3(int* __restrict__ off,
                                               const int* __restrict__ bsum,
                                               int n) {
    int i = blockIdx.x * 256 + threadIdx.x;
    if (i < n) off[i] += bsum[i >> 10];
}

__global__ __launch_bounds__(256) void k_fill(const int* __restrict__ rows,
                                              const int* __restrict__ cols,
                                              const float* __restrict__ dinv,
                                              const int* __restrict__ off,
                                              int* __restrict__ cursor,
                                              int* __restrict__ col_s,
                                              float* __restrict__ w_s, int e) {
    int i = blockIdx.x * 256 + threadIdx.x;
    if (i < e) {
        int r = rows[i], c = cols[i];
        int pos = off[r] + atomicAdd(&cursor[r], 1);
        col_s[pos] = c;
        w_s[pos] = dinv[r] * dinv[c];
    }
}

// weight convert+transpose: W [K][128] fp32 -> Wt [128][K] bf16
__global__ __launch_bounds__(256) void k_wt(const float* __restrict__ W,
                                            unsigned short* __restrict__ Wt,
                                            int K) {
    int i = blockIdx.x * 256 + threadIdx.x;
    if (i < K * 128) {
        int k = i >> 7, n = i & 127;
        Wt[n * K + k] = f2bf(W[i]);
    }
}

// ---------------------------------------------------------------------------
// SpMM (bf16): y[i] = dinv[i]^2*z[i] + sum_e w_e * z[col_e]
// One wave per node. Wave = 4 edge-groups x 16 feature-lanes; each lane
// gathers ushort8 (16B); 2-deep unroll -> 8 gathers in flight per wave.
// Cross-group reduce via shfl_xor(16|32); group 0 writes the row.
// ---------------------------------------------------------------------------
__global__ __launch_bounds__(256) void k_spmm(
    const unsigned short* __restrict__ z, unsigned short* __restrict__ y,
    const int* __restrict__ off, const int* __restrict__ cols,
    const float* __restrict__ w, const float* __restrict__ dinv, int n) {
    const int node = blockIdx.x * 4 + (threadIdx.x >> 6);
    if (node >= n) return;
    const int lane = threadIdx.x & 63;
    const int g = lane >> 4;  // edge slot 0..3
    const int l = lane & 15;  // feature slice 0..15 (8 feats each)

    float acc[8];
#pragma unroll
    for (int j = 0; j < 8; j++) acc[j] = 0.0f;

    const int p0 = off[node], p1 = off[node + 1];
    int p = p0 + g;
    for (; p + 4 < p1; p += 8) {  // two edges per group in flight
        const int c0 = cols[p], c1 = cols[p + 4];
        const float w0 = w[p], w1 = w[p + 4];
        const ushort8 t0 = *(const ushort8*)(z + (size_t)c0 * HF + 8 * l);
        const ushort8 t1 = *(const ushort8*)(z + (size_t)c1 * HF + 8 * l);
#pragma unroll
        for (int j = 0; j < 8; j++) acc[j] = fmaf(w0, b2f(t0[j]), acc[j]);
#pragma unroll
        for (int j = 0; j < 8; j++) acc[j] = fmaf(w1, b2f(t1[j]), acc[j]);
    }
    if (p < p1) {  // at most one leftover edge per group
        const int c0 = cols[p];
        const float w0 = w[p];
        const ushort8 t0 = *(const ushort8*)(z + (size_t)c0 * HF + 8 * l);
#pragma unroll
        for (int j = 0; j < 8; j++) acc[j] = fmaf(w0, b2f(t0[j]), acc[j]);
    }
    if (g == 0) {  // self loop: dinv^2 * z[node]
        const float di = dinv[node];
        const ushort8 v = *(const ushort8*)(z + (size_t)node * HF + 8 * l);
        const float d2 = di * di;
#pragma unroll
        for (int j = 0; j < 8; j++) acc[j] = fmaf(d2, b2f(v[j]), acc[j]);
    }
#pragma unroll
    for (int j = 0; j < 8; j++) {
        acc[j] += __shfl_xor(acc[j], 16);
        acc[j] += __shfl_xor(acc[j], 32);
    }
    if (g == 0) {
        ushort8 o;
#pragma unroll
        for (int j = 0; j < 8; j++) o[j] = f2bf(acc[j]);
        *(ushort8*)(y + (size_t)node * HF + 8 * l) = o;
    }
}

// ---------------------------------------------------------------------------
// MFMA GEMM (M x K @ K x 128) + optional row-L2-normalize of A (epilogue
// scale) + bias + LayerNorm + ReLU.  A: fp32 or bf16; out: fp32 or bf16.
// Block 256 = 4 waves. BM=64 (wave w: rows 16w..16w+15), BN=128, BK=32.
// ---------------------------------------------------------------------------
template <int K, bool NORM, typename AT, typename OT>
__global__ __launch_bounds__(256) void gemm_mfma(
    const AT* __restrict__ A, int lda, const unsigned short* __restrict__ Wt,
    const float* __restrict__ bias, const float* __restrict__ g,
    const float* __restrict__ be, OT* __restrict__ out, int ldo, int M) {
    constexpr int LDT = 40;  // row stride in shorts (32 + 8 pad, 16B aligned)
    __shared__ unsigned short Ast[64][LDT];
    __shared__ unsigned short Bst[128][LDT];
    __shared__ float rn_s[64];

    const int tid = threadIdx.x;
    const int row0 = blockIdx.x * 64;
    const int w = tid >> 6;
    const int lane = tid & 63;
    const int m = lane & 15;
    const int q = lane >> 4;
    const int lrow = tid >> 2;  // stager row 0..63
    const int lq = tid & 3;     // stager k-octet

    f32x4 acc[8];
#pragma unroll
    for (int t = 0; t < 8; t++) acc[t] = (f32x4){0.f, 0.f, 0.f, 0.f};

    float sumsq = 0.0f;
    const bool arow_ok = (row0 + lrow) < M;

    for (int k0 = 0; k0 < K; k0 += 32) {
        __syncthreads();
        // ---- stage A tile (64 x 32) -> bf16 LDS
        ushort8 pk;
        if constexpr (sizeof(AT) == 4) {  // fp32 A with on-the-fly cvt
            f32x4 a0 = (f32x4){0.f, 0.f, 0.f, 0.f}, a1 = a0;
            if (arow_ok) {
                const float* Ap =
                    (const float*)A + (size_t)(row0 + lrow) * lda + k0 + 8 * lq;
                a0 = *(const f32x4*)Ap;
                a1 = *(const f32x4*)(Ap + 4);
            }
            if (NORM) {
#pragma unroll
                for (int j = 0; j < 4; j++)
                    sumsq += a0[j] * a0[j] + a1[j] * a1[j];
            }
#pragma unroll
            for (int j = 0; j < 4; j++) {
                pk[j] = f2bf(a0[j]);
                pk[j + 4] = f2bf(a1[j]);
            }
        } else {  // bf16 A
            pk = (ushort8){0, 0, 0, 0, 0, 0, 0, 0};
            if (arow_ok)
                pk = *(const ushort8*)((const unsigned short*)A +
                                       (size_t)(row0 + lrow) * lda + k0 +
                                       8 * lq);
        }
        *(ushort8*)&Ast[lrow][8 * lq] = pk;
        // ---- stage B tile (128 x 32) from Wt[128][K]
#pragma unroll
        for (int j = 0; j < 2; j++) {
            int c = tid + 256 * j;  // 512 chunks of 16B
            int nn = c >> 2, qq = c & 3;
            ushort8 bchunk =
                *(const ushort8*)(Wt + (size_t)nn * K + k0 + 8 * qq);
            *(ushort8*)&Bst[nn][8 * qq] = bchunk;
        }
        __syncthreads();
        // ---- compute: 8 n-tiles per wave
        bf16x8 af = *(const bf16x8*)&Ast[16 * w + m][8 * q];
#pragma unroll
        for (int t = 0; t < 8; t++) {
            bf16x8 bfv = *(const bf16x8*)&Bst[16 * t + m][8 * q];
            acc[t] = __builtin_amdgcn_mfma_f32_16x16x32_bf16(af, bfv, acc[t], 0,
                                                             0, 0);
        }
    }

    if (NORM) {
        sumsq += __shfl_xor(sumsq, 1);
        sumsq += __shfl_xor(sumsq, 2);
        if (lq == 0) rn_s[lrow] = 1.0f / fmaxf(sqrtf(sumsq), 1e-12f);
        __syncthreads();
    }

    // ---- epilogue: bias + LN + ReLU
    float bb[8], gg[8], ee[8];
#pragma unroll
    for (int t = 0; t < 8; t++) {
        bb[t] = bias[16 * t + m];
        gg[t] = g[16 * t + m];
        ee[t] = be[16 * t + m];
    }
#pragma unroll
    for (int r = 0; r < 4; r++) {
        const int lrow2 = 16 * w + 4 * q + r;  // block-local row
        float rn = 1.0f;
        if (NORM) rn = rn_s[lrow2];
        float s1 = 0.f, s2 = 0.f;
#pragma unroll
        for (int t = 0; t < 8; t++) {
            float y = fmaf(acc[t][r], rn, bb[t]);
            s1 += y;
            s2 = fmaf(y, y, s2);
        }
#pragma unroll
        for (int mask = 1; mask <= 8; mask <<= 1) {
            s1 += __shfl_xor(s1, mask);
            s2 += __shfl_xor(s2, mask);
        }
        const float mean = s1 * (1.0f / 128.0f);
        const float var = fmaxf(s2 * (1.0f / 128.0f) - mean * mean, 0.0f);
        const float rstd = rsqrtf(var + 1e-5f);
        const int grow = row0 + lrow2;
        if (grow < M) {
#pragma unroll
            for (int t = 0; t < 8; t++) {
                float y = fmaf(acc[t][r], rn, bb[t]);
                float o = fmaxf(fmaf((y - mean) * rstd, gg[t], ee[t]), 0.0f);
                if constexpr (sizeof(OT) == 2)
                    ((unsigned short*)out)[(size_t)grow * ldo + 16 * t + m] =
                        f2bf(o);
                else
                    ((float*)out)[(size_t)grow * ldo + 16 * t + m] = o;
            }
        }
    }
}

// ---------------------------------------------------------------------------
extern "C" void kernel_launch(void* const* d_in, const int* in_sizes, int n_in,
                              void* d_out, int out_size, void* d_ws,
                              size_t ws_size, hipStream_t stream) {
    const int* ei = (const int*)d_in[0];          // [2, E]
    const float* feats = (const float*)d_in[1];   // [N, 512]
    const float* W_uni = (const float*)d_in[2];   // [512,128]
    const float* b_uni = (const float*)d_in[3];
    const float* g_uni = (const float*)d_in[4];
    const float* be_uni = (const float*)d_in[5];
    const float* W_ind = (const float*)d_in[6];   // [4,128,128]
    const float* b_ind = (const float*)d_in[7];   // [4,128]
    const float* g_ind = (const float*)d_in[8];
    const float* be_ind = (const float*)d_in[9];
    const float* W_rel = (const float*)d_in[10];  // [512,128]
    const float* b_rel = (const float*)d_in[11];
    const float* g_rel = (const float*)d_in[12];
    const float* be_rel = (const float*)d_in[13];
    float* out = (float*)d_out;

    char* p = (char*)d_ws;
    auto alloc = [&](size_t bytes) {
        void* r = (void*)p;
        p += (bytes + 255) & ~(size_t)255;
        return r;
    };
    int* deg = (int*)alloc(NN * 4);
    int* cursor = (int*)alloc(NN * 4);
    int* off = (int*)alloc((NN + 1) * 4);
    int* bsum = (int*)alloc(1024 * 4);
    int* col_s = (int*)alloc((size_t)NE * 4);
    float* w_s = (float*)alloc((size_t)NE * 4);
    float* dinv = (float*)alloc(NN * 4);
    unsigned short* Wt_uni = (unsigned short*)alloc(128 * FE * 2);
    unsigned short* Wt_rel = (unsigned short*)alloc(128 * (NNIE * HF) * 2);
    unsigned short* Wt_ind = (unsigned short*)alloc(NNIE * HF * HF * 2);
    unsigned short* h = (unsigned short*)alloc((size_t)NN * HF * 2);
    unsigned short* za = (unsigned short*)alloc((size_t)NN * HF * 2);
    unsigned short* zb = (unsigned short*)alloc((size_t)NN * HF * 2);
    unsigned short* cat = (unsigned short*)alloc((size_t)NN * NNIE * HF * 2);

    const int gE = (NE + 255) / 256;
    const int gN = (NN + 255) / 256;
    const int gGemm = (NN + 63) / 64;
    const int gSpmm = (NN + 3) / 4;
    const int nbScan = (NN + 1023) / 1024;
    const int* erow = ei;
    const int* ecol = ei + NE;

    // graph prep
    k_zero<<<gN, 256, 0, stream>>>(deg, cursor, NN);
    k_count<<<gE, 256, 0, stream>>>(erow, deg, NE);
    k_dinv<<<gN, 256, 0, stream>>>(deg, dinv, NN);
    k_scan1<<<nbScan, 1024, 0, stream>>>(deg, off, bsum, NN);
    k_scan2<<<1, 1024, 0, stream>>>(bsum, nbScan, off + NN);
    k_scan3<<<gN, 256, 0, stream>>>(off, bsum, NN);
    k_fill<<<gE, 256, 0, stream>>>(erow, ecol, dinv, off, cursor, col_s, w_s,
                                   NE);

    // weight transpose+cvt (tiny)
    k_wt<<<(FE * 128 + 255) / 256, 256, 0, stream>>>(W_uni, Wt_uni, FE);
    k_wt<<<(NNIE * HF * 128 + 255) / 256, 256, 0, stream>>>(W_rel, Wt_rel,
                                                            NNIE * HF);
    for (int hh = 0; hh < NNIE; hh++)
        k_wt<<<(HF * 128 + 255) / 256, 256, 0, stream>>>(
            W_ind + hh * HF * HF, Wt_ind + hh * HF * HF, HF);

    // unified transform: h = relu(LN(normalize(x) @ W_uni + b))
    gemm_mfma<FE, true, float, unsigned short>
        <<<gGemm, 256, 0, stream>>>(feats, FE, Wt_uni, b_uni, g_uni, be_uni, h,
                                    HF, NN);
    // hop 0
    gemm_mfma<HF, false, unsigned short, unsigned short>
        <<<gGemm, 256, 0, stream>>>(h, HF, Wt_ind + 0 * HF * HF, b_ind, g_ind,
                                    be_ind, cat + 0 * HF, NNIE * HF, NN);
    // hop 1
    k_spmm<<<gSpmm, 256, 0, stream>>>(h, za, off, col_s, w_s, dinv, NN);
    gemm_mfma<HF, false, unsigned short, unsigned short>
        <<<gGemm, 256, 0, stream>>>(za, HF, Wt_ind + 1 * HF * HF, b_ind + HF,
                                    g_ind + HF, be_ind + HF, cat + 1 * HF,
                                    NNIE * HF, NN);
    // hop 2
    k_spmm<<<gSpmm, 256, 0, stream>>>(za, zb, off, col_s, w_s, dinv, NN);
    gemm_mfma<HF, false, unsigned short, unsigned short>
        <<<gGemm, 256, 0, stream>>>(zb, HF, Wt_ind + 2 * HF * HF,
                                    b_ind + 2 * HF, g_ind + 2 * HF,
                                    be_ind + 2 * HF, cat + 2 * HF, NNIE * HF,
                                    NN);
    // hop 3
    k_spmm<<<gSpmm, 256, 0, stream>>>(zb, za, off, col_s, w_s, dinv, NN);
    gemm_mfma<HF, false, unsigned short, unsigned short>
        <<<gGemm, 256, 0, stream>>>(za, HF, Wt_ind + 3 * HF * HF,
                                    b_ind + 3 * HF, g_ind + 3 * HF,
                                    be_ind + 3 * HF, cat + 3 * HF, NNIE * HF,
                                    NN);
    // relation network
    gemm_mfma<NNIE * HF, false, unsigned short, float>
        <<<gGemm, 256, 0, stream>>>(cat, NNIE * HF, Wt_rel, b_rel, g_rel,
                                    be_rel, out, HF, NN);
}

// Round 4
// 791.163 us; speedup vs baseline: 2.0927x; 1.0397x over previous
//
#include <hip/hip_runtime.h>
#include <hip/hip_bf16.h>

// Problem constants (match reference)
#define NN 100000      // nodes
#define FE 512         // in_feats
#define HF 128         // h_feats
#define NE 1600000     // edges
#define NNIE 4         // hops+1

typedef __attribute__((ext_vector_type(8))) __bf16 bf16x8;
typedef __attribute__((ext_vector_type(4))) float f32x4;
typedef __attribute__((ext_vector_type(8))) unsigned short ushort8;

__device__ __forceinline__ unsigned short f2bf(float f) {
    unsigned u = __float_as_uint(f);
    unsigned r = (u + 0x7fffu + ((u >> 16) & 1u)) >> 16;  // RNE
    return (unsigned short)r;
}
__device__ __forceinline__ float b2f(unsigned short u) {
    return __uint_as_float(((unsigned)u) << 16);
}

// ---------------------------------------------------------------------------
// Graph preprocessing
// ---------------------------------------------------------------------------
__global__ __launch_bounds__(256) void k_zero(int* __restrict__ deg,
                                              int* __restrict__ cursor, int n) {
    int i = blockIdx.x * 256 + threadIdx.x;
    if (i < n) { deg[i] = 0; cursor[i] = 0; }
}

__global__ __launch_bounds__(256) void k_count(const int* __restrict__ row,
                                               int* __restrict__ deg, int e) {
    int i = blockIdx.x * 256 + threadIdx.x;
    if (i < e) atomicAdd(&deg[row[i]], 1);
}

// ---- multi-block exclusive scan (3 passes); pass 1 also computes dinv -----
__global__ __launch_bounds__(1024) void k_scan1(const int* __restrict__ cnt,
                                                int* __restrict__ off,
                                                int* __restrict__ bsum,
                                                float* __restrict__ dinv,
                                                int n) {
    __shared__ int wsum[16];
    const int tid = threadIdx.x, lane = tid & 63, wid = tid >> 6;
    const int i = blockIdx.x * 1024 + tid;
    const int v = (i < n) ? cnt[i] : 0;
    if (i < n) dinv[i] = rsqrtf((float)(v + 1));  // +1 self loop
    int x = v;
#pragma unroll
    for (int s = 1; s < 64; s <<= 1) {
        int t = __shfl_up(x, s);
        if (lane >= s) x += t;
    }
    if (lane == 63) wsum[wid] = x;
    __syncthreads();
    if (wid == 0 && lane < 16) {
        int t = wsum[lane];
#pragma unroll
        for (int s = 1; s < 16; s <<= 1) {
            int u = __shfl_up(t, s);
            if (lane >= s) t += u;
        }
        wsum[lane] = t;
    }
    __syncthreads();
    const int wexc = (wid == 0) ? 0 : wsum[wid - 1];
    if (i < n) off[i] = wexc + x - v;  // block-local exclusive
    if (tid == 0) bsum[blockIdx.x] = wsum[15];
}
__global__ __launch_bounds__(1024) void k_scan2(int* __restrict__ bsum, int nb,
                                                int* __restrict__ total_out) {
    __shared__ int wsum[16];
    const int tid = threadIdx.x, lane = tid & 63, wid = tid >> 6;
    const int v = (tid < nb) ? bsum[tid] : 0;
    int x = v;
#pragma unroll
    for (int s = 1; s < 64; s <<= 1) {
        int t = __shfl_up(x, s);
        if (lane >= s) x += t;
    }
    if (lane == 63) wsum[wid] = x;
    __syncthreads();
    if (wid == 0 && lane < 16) {
        int t = wsum[lane];
#pragma unroll
        for (int s = 1; s < 16; s <<= 1) {
            int u = __shfl_up(t, s);
            if (lane >= s) t += u;
        }
        wsum[lane] = t;
    }
    __syncthreads();
    const int wexc = (wid == 0) ? 0 : wsum[wid - 1];
    if (tid < nb) bsum[tid] = wexc + x - v;
    if (tid == 0) *total_out = wsum[15];
}
__global__ __launch_bounds__(256) void k_scan3(int* __restrict__ off,
                                               const int* __restrict__ bsum,
                                               int n) {
    int i = blockIdx.x * 256 + threadIdx.x;
    if (i < n) off[i] += bsum[i >> 10];
}

// fill interleaved (col, weight) edge records
__global__ __launch_bounds__(256) void k_fill(const int* __restrict__ rows,
                                              const int* __restrict__ cols,
                                              const float* __restrict__ dinv,
                                              const int* __restrict__ off,
                                              int* __restrict__ cursor,
                                              int2* __restrict__ es, int e) {
    int i = blockIdx.x * 256 + threadIdx.x;
    if (i < e) {
        int r = rows[i], c = cols[i];
        int pos = off[r] + atomicAdd(&cursor[r], 1);
        es[pos] = make_int2(c, __float_as_int(dinv[r] * dinv[c]));
    }
}

// all weight transposes+cvt in one launch:
// region 0: W_uni [512][128] -> Tu [128][512]
// region 1: W_rel [512][128] -> Tr [128][512]
// region 2: W_ind [4][128][128] -> Ti [4][128][128] (per-hop transpose)
__global__ __launch_bounds__(256) void k_wt_all(
    const float* __restrict__ Wu, const float* __restrict__ Wr,
    const float* __restrict__ Wi, unsigned short* __restrict__ Tu,
    unsigned short* __restrict__ Tr, unsigned short* __restrict__ Ti) {
    int i = blockIdx.x * 256 + threadIdx.x;
    if (i < 65536) {
        int k = i >> 7, n = i & 127;
        Tu[n * 512 + k] = f2bf(Wu[i]);
    } else if (i < 131072) {
        int j = i - 65536;
        int k = j >> 7, n = j & 127;
        Tr[n * 512 + k] = f2bf(Wr[j]);
    } else if (i < 196608) {
        int j = i - 131072;
        int hh = j >> 14, r = j & 16383;
        int k = r >> 7, n = r & 127;
        Ti[hh * 16384 + n * 128 + k] = f2bf(Wi[j]);
    }
}

// ---------------------------------------------------------------------------
// SpMM (bf16): y[i] = dinv[i]^2*z[i] + sum_e w_e * z[col_e]
// One wave per node. Wave = 4 edge-groups x 16 feature-lanes; each lane
// gathers ushort8 (16B); 4-deep unroll -> up to 16 gathers in flight.
// ---------------------------------------------------------------------------
__global__ __launch_bounds__(256) void k_spmm(
    const unsigned short* __restrict__ z, unsigned short* __restrict__ y,
    const int* __restrict__ off, const int2* __restrict__ es,
    const float* __restrict__ dinv, int n) {
    const int node = blockIdx.x * 4 + (threadIdx.x >> 6);
    if (node >= n) return;
    const int lane = threadIdx.x & 63;
    const int g = lane >> 4;  // edge slot 0..3
    const int l = lane & 15;  // feature slice (8 feats)

    float acc[8];
#pragma unroll
    for (int j = 0; j < 8; j++) acc[j] = 0.0f;

    const int p0 = off[node], p1 = off[node + 1];
    int p = p0 + g;
    for (; p + 12 < p1; p += 16) {  // 4 edges per group in flight
        const int2 e0 = es[p], e1 = es[p + 4], e2 = es[p + 8], e3 = es[p + 12];
        const ushort8 t0 = *(const ushort8*)(z + (size_t)e0.x * HF + 8 * l);
        const ushort8 t1 = *(const ushort8*)(z + (size_t)e1.x * HF + 8 * l);
        const ushort8 t2 = *(const ushort8*)(z + (size_t)e2.x * HF + 8 * l);
        const ushort8 t3 = *(const ushort8*)(z + (size_t)e3.x * HF + 8 * l);
        const float w0 = __int_as_float(e0.y), w1 = __int_as_float(e1.y);
        const float w2 = __int_as_float(e2.y), w3 = __int_as_float(e3.y);
#pragma unroll
        for (int j = 0; j < 8; j++) acc[j] = fmaf(w0, b2f(t0[j]), acc[j]);
#pragma unroll
        for (int j = 0; j < 8; j++) acc[j] = fmaf(w1, b2f(t1[j]), acc[j]);
#pragma unroll
        for (int j = 0; j < 8; j++) acc[j] = fmaf(w2, b2f(t2[j]), acc[j]);
#pragma unroll
        for (int j = 0; j < 8; j++) acc[j] = fmaf(w3, b2f(t3[j]), acc[j]);
    }
    for (; p + 4 < p1; p += 8) {  // 2 edges per group
        const int2 e0 = es[p], e1 = es[p + 4];
        const ushort8 t0 = *(const ushort8*)(z + (size_t)e0.x * HF + 8 * l);
        const ushort8 t1 = *(const ushort8*)(z + (size_t)e1.x * HF + 8 * l);
        const float w0 = __int_as_float(e0.y), w1 = __int_as_float(e1.y);
#pragma unroll
        for (int j = 0; j < 8; j++) acc[j] = fmaf(w0, b2f(t0[j]), acc[j]);
#pragma unroll
        for (int j = 0; j < 8; j++) acc[j] = fmaf(w1, b2f(t1[j]), acc[j]);
    }
    if (p < p1) {
        const int2 e0 = es[p];
        const ushort8 t0 = *(const ushort8*)(z + (size_t)e0.x * HF + 8 * l);
        const float w0 = __int_as_float(e0.y);
#pragma unroll
        for (int j = 0; j < 8; j++) acc[j] = fmaf(w0, b2f(t0[j]), acc[j]);
    }
    if (g == 0) {  // self loop: dinv^2 * z[node]
        const float di = dinv[node];
        const ushort8 v = *(const ushort8*)(z + (size_t)node * HF + 8 * l);
        const float d2 = di * di;
#pragma unroll
        for (int j = 0; j < 8; j++) acc[j] = fmaf(d2, b2f(v[j]), acc[j]);
    }
#pragma unroll
    for (int j = 0; j < 8; j++) {
        acc[j] += __shfl_xor(acc[j], 16);
        acc[j] += __shfl_xor(acc[j], 32);
    }
    if (g == 0) {
        ushort8 o;
#pragma unroll
        for (int j = 0; j < 8; j++) o[j] = f2bf(acc[j]);
        *(ushort8*)(y + (size_t)node * HF + 8 * l) = o;
    }
}

// ---------------------------------------------------------------------------
// MFMA GEMM (M x K @ K x 128), K multiple of 64, BK=64 + optional row-L2-
// normalize of A (epilogue scale) + bias + LayerNorm + ReLU.
// Block 256 = 4 waves. BM=64 (wave w: rows 16w..16w+15), BN=128.
// ---------------------------------------------------------------------------
template <int K, bool NORM, typename AT, typename OT>
__global__ __launch_bounds__(256) void gemm_mfma(
    const AT* __restrict__ A, int lda, const unsigned short* __restrict__ Wt,
    const float* __restrict__ bias, const float* __restrict__ g,
    const float* __restrict__ be, OT* __restrict__ out, int ldo, int M) {
    constexpr int LDT = 72;  // 64 + 8 pad shorts
    __shared__ unsigned short Ast[64][LDT];
    __shared__ unsigned short Bst[128][LDT];
    __shared__ float rn_s[64];

    const int tid = threadIdx.x;
    const int row0 = blockIdx.x * 64;
    const int w = tid >> 6;
    const int lane = tid & 63;
    const int m = lane & 15;
    const int q = lane >> 4;
    const int lrow = tid >> 2;  // stager row 0..63
    const int lq = tid & 3;

    f32x4 acc[8];
#pragma unroll
    for (int t = 0; t < 8; t++) acc[t] = (f32x4){0.f, 0.f, 0.f, 0.f};

    float sumsq = 0.0f;
    const bool arow_ok = (row0 + lrow) < M;

    for (int k0 = 0; k0 < K; k0 += 64) {
        __syncthreads();
        // ---- stage A tile (64 x 64): 2 octets per thread
#pragma unroll
        for (int oo = 0; oo < 2; oo++) {
            const int o = lq + 4 * oo;
            ushort8 pk;
            if constexpr (sizeof(AT) == 4) {
                f32x4 a0 = (f32x4){0.f, 0.f, 0.f, 0.f}, a1 = a0;
                if (arow_ok) {
                    const float* Ap = (const float*)A +
                                      (size_t)(row0 + lrow) * lda + k0 + 8 * o;
                    a0 = *(const f32x4*)Ap;
                    a1 = *(const f32x4*)(Ap + 4);
                }
                if (NORM) {
#pragma unroll
                    for (int j = 0; j < 4; j++)
                        sumsq += a0[j] * a0[j] + a1[j] * a1[j];
                }
#pragma unroll
                for (int j = 0; j < 4; j++) {
                    pk[j] = f2bf(a0[j]);
                    pk[j + 4] = f2bf(a1[j]);
                }
            } else {
                pk = (ushort8){0, 0, 0, 0, 0, 0, 0, 0};
                if (arow_ok)
                    pk = *(const ushort8*)((const unsigned short*)A +
                                           (size_t)(row0 + lrow) * lda + k0 +
                                           8 * o);
            }
            *(ushort8*)&Ast[lrow][8 * o] = pk;
        }
        // ---- stage B tile (128 x 64): 4 octets per thread
        const int bn = tid >> 1;
#pragma unroll
        for (int kk = 0; kk < 4; kk++) {
            const int o = (tid & 1) + 2 * kk;
            *(ushort8*)&Bst[bn][8 * o] =
                *(const ushort8*)(Wt + (size_t)bn * K + k0 + 8 * o);
        }
        __syncthreads();
        // ---- compute: 2 k-steps x 8 n-tiles
#pragma unroll
        for (int jj = 0; jj < 2; jj++) {
            bf16x8 af = *(const bf16x8*)&Ast[16 * w + m][8 * q + 32 * jj];
#pragma unroll
            for (int t = 0; t < 8; t++) {
                bf16x8 bfv = *(const bf16x8*)&Bst[16 * t + m][8 * q + 32 * jj];
                acc[t] = __builtin_amdgcn_mfma_f32_16x16x32_bf16(af, bfv,
                                                                 acc[t], 0, 0,
                                                                 0);
            }
        }
    }

    if (NORM) {
        sumsq += __shfl_xor(sumsq, 1);
        sumsq += __shfl_xor(sumsq, 2);
        if (lq == 0) rn_s[lrow] = 1.0f / fmaxf(sqrtf(sumsq), 1e-12f);
        __syncthreads();
    }

    float bb[8], gg[8], ee[8];
#pragma unroll
    for (int t = 0; t < 8; t++) {
        bb[t] = bias[16 * t + m];
        gg[t] = g[16 * t + m];
        ee[t] = be[16 * t + m];
    }
#pragma unroll
    for (int r = 0; r < 4; r++) {
        const int lrow2 = 16 * w + 4 * q + r;
        float rn = 1.0f;
        if (NORM) rn = rn_s[lrow2];
        float s1 = 0.f, s2 = 0.f;
#pragma unroll
        for (int t = 0; t < 8; t++) {
            float y = fmaf(acc[t][r], rn, bb[t]);
            s1 += y;
            s2 = fmaf(y, y, s2);
        }
#pragma unroll
        for (int mask = 1; mask <= 8; mask <<= 1) {
            s1 += __shfl_xor(s1, mask);
            s2 += __shfl_xor(s2, mask);
        }
        const float mean = s1 * (1.0f / 128.0f);
        const float var = fmaxf(s2 * (1.0f / 128.0f) - mean * mean, 0.0f);
        const float rstd = rsqrtf(var + 1e-5f);
        const int grow = row0 + lrow2;
        if (grow < M) {
#pragma unroll
            for (int t = 0; t < 8; t++) {
                float y = fmaf(acc[t][r], rn, bb[t]);
                float o = fmaxf(fmaf((y - mean) * rstd, gg[t], ee[t]), 0.0f);
                if constexpr (sizeof(OT) == 2)
                    ((unsigned short*)out)[(size_t)grow * ldo + 16 * t + m] =
                        f2bf(o);
                else
                    ((float*)out)[(size_t)grow * ldo + 16 * t + m] = o;
            }
        }
    }
}

// ---------------------------------------------------------------------------
// Specialized K=128 GEMM: whole B (128x128) + A tile staged once; 1 barrier.
// bf16 in, bf16 out (cat slice), bias+LN+ReLU epilogue.
// ---------------------------------------------------------------------------
__global__ __launch_bounds__(256) void gemm128(
    const unsigned short* __restrict__ A,
    const unsigned short* __restrict__ Wt, const float* __restrict__ bias,
    const float* __restrict__ g, const float* __restrict__ be,
    unsigned short* __restrict__ out, int ldo, int M) {
    constexpr int LDT = 136;  // 128 + 8 pad
    __shared__ unsigned short Ast[64][LDT];
    __shared__ unsigned short Bst[128][LDT];

    const int tid = threadIdx.x;
    const int row0 = blockIdx.x * 64;
    const int w = tid >> 6;
    const int lane = tid & 63;
    const int m = lane & 15;
    const int q = lane >> 4;
    const int lrow = tid >> 2;
    const int lq = tid & 3;

    const bool arow_ok = (row0 + lrow) < M;
#pragma unroll
    for (int k = 0; k < 4; k++) {
        const int o = lq + 4 * k;
        ushort8 pk = (ushort8){0, 0, 0, 0, 0, 0, 0, 0};
        if (arow_ok)
            pk = *(const ushort8*)(A + (size_t)(row0 + lrow) * HF + 8 * o);
        *(ushort8*)&Ast[lrow][8 * o] = pk;
    }
    const int bn = tid >> 1;
#pragma unroll
    for (int k = 0; k < 8; k++) {
        const int o = (tid & 1) + 2 * k;
        *(ushort8*)&Bst[bn][8 * o] =
            *(const ushort8*)(Wt + (size_t)bn * HF + 8 * o);
    }
    __syncthreads();

    f32x4 acc[8];
#pragma unroll
    for (int t = 0; t < 8; t++) acc[t] = (f32x4){0.f, 0.f, 0.f, 0.f};
#pragma unroll
    for (int jj = 0; jj < 4; jj++) {
        bf16x8 af = *(const bf16x8*)&Ast[16 * w + m][8 * q + 32 * jj];
#pragma unroll
        for (int t = 0; t < 8; t++) {
            bf16x8 bfv = *(const bf16x8*)&Bst[16 * t + m][8 * q + 32 * jj];
            acc[t] = __builtin_amdgcn_mfma_f32_16x16x32_bf16(af, bfv, acc[t], 0,
                                                             0, 0);
        }
    }

    float bb[8], gg[8], ee[8];
#pragma unroll
    for (int t = 0; t < 8; t++) {
        bb[t] = bias[16 * t + m];
        gg[t] = g[16 * t + m];
        ee[t] = be[16 * t + m];
    }
#pragma unroll
    for (int r = 0; r < 4; r++) {
        const int lrow2 = 16 * w + 4 * q + r;
        float s1 = 0.f, s2 = 0.f;
#pragma unroll
        for (int t = 0; t < 8; t++) {
            float y = acc[t][r] + bb[t];
            s1 += y;
            s2 = fmaf(y, y, s2);
        }
#pragma unroll
        for (int mask = 1; mask <= 8; mask <<= 1) {
            s1 += __shfl_xor(s1, mask);
            s2 += __shfl_xor(s2, mask);
        }
        const float mean = s1 * (1.0f / 128.0f);
        const float var = fmaxf(s2 * (1.0f / 128.0f) - mean * mean, 0.0f);
        const float rstd = rsqrtf(var + 1e-5f);
        const int grow = row0 + lrow2;
        if (grow < M) {
#pragma unroll
            for (int t = 0; t < 8; t++) {
                float y = acc[t][r] + bb[t];
                float o = fmaxf(fmaf((y - mean) * rstd, gg[t], ee[t]), 0.0f);
                out[(size_t)grow * ldo + 16 * t + m] = f2bf(o);
            }
        }
    }
}

// ---------------------------------------------------------------------------
extern "C" void kernel_launch(void* const* d_in, const int* in_sizes, int n_in,
                              void* d_out, int out_size, void* d_ws,
                              size_t ws_size, hipStream_t stream) {
    const int* ei = (const int*)d_in[0];          // [2, E]
    const float* feats = (const float*)d_in[1];   // [N, 512]
    const float* W_uni = (const float*)d_in[2];   // [512,128]
    const float* b_uni = (const float*)d_in[3];
    const float* g_uni = (const float*)d_in[4];
    const float* be_uni = (const float*)d_in[5];
    const float* W_ind = (const float*)d_in[6];   // [4,128,128]
    const float* b_ind = (const float*)d_in[7];
    const float* g_ind = (const float*)d_in[8];
    const float* be_ind = (const float*)d_in[9];
    const float* W_rel = (const float*)d_in[10];  // [512,128]
    const float* b_rel = (const float*)d_in[11];
    const float* g_rel = (const float*)d_in[12];
    const float* be_rel = (const float*)d_in[13];
    float* out = (float*)d_out;

    char* p = (char*)d_ws;
    auto alloc = [&](size_t bytes) {
        void* r = (void*)p;
        p += (bytes + 255) & ~(size_t)255;
        return r;
    };
    int* deg = (int*)alloc(NN * 4);
    int* cursor = (int*)alloc(NN * 4);
    int* off = (int*)alloc((NN + 1) * 4);
    int* bsum = (int*)alloc(1024 * 4);
    int2* es = (int2*)alloc((size_t)NE * 8);
    float* dinv = (float*)alloc(NN * 4);
    unsigned short* Wt_uni = (unsigned short*)alloc(128 * FE * 2);
    unsigned short* Wt_rel = (unsigned short*)alloc(128 * (NNIE * HF) * 2);
    unsigned short* Wt_ind = (unsigned short*)alloc(NNIE * HF * HF * 2);
    unsigned short* h = (unsigned short*)alloc((size_t)NN * HF * 2);
    unsigned short* za = (unsigned short*)alloc((size_t)NN * HF * 2);
    unsigned short* zb = (unsigned short*)alloc((size_t)NN * HF * 2);
    unsigned short* cat = (unsigned short*)alloc((size_t)NN * NNIE * HF * 2);

    const int gE = (NE + 255) / 256;
    const int gN = (NN + 255) / 256;
    const int gGemm = (NN + 63) / 64;
    const int gSpmm = (NN + 3) / 4;
    const int nbScan = (NN + 1023) / 1024;
    const int* erow = ei;
    const int* ecol = ei + NE;

    // graph prep
    k_zero<<<gN, 256, 0, stream>>>(deg, cursor, NN);
    k_count<<<gE, 256, 0, stream>>>(erow, deg, NE);
    k_scan1<<<nbScan, 1024, 0, stream>>>(deg, off, bsum, dinv, NN);
    k_scan2<<<1, 1024, 0, stream>>>(bsum, nbScan, off + NN);
    k_scan3<<<gN, 256, 0, stream>>>(off, bsum, NN);
    k_fill<<<gE, 256, 0, stream>>>(erow, ecol, dinv, off, cursor, es, NE);

    // weight transpose+cvt: one launch for all
    k_wt_all<<<(196608 + 255) / 256, 256, 0, stream>>>(W_uni, W_rel, W_ind,
                                                       Wt_uni, Wt_rel, Wt_ind);

    // unified transform: h = relu(LN(normalize(x) @ W_uni + b))
    gemm_mfma<FE, true, float, unsigned short>
        <<<gGemm, 256, 0, stream>>>(feats, FE, Wt_uni, b_uni, g_uni, be_uni, h,
                                    HF, NN);
    // hop 0
    gemm128<<<gGemm, 256, 0, stream>>>(h, Wt_ind + 0 * HF * HF, b_ind, g_ind,
                                       be_ind, cat + 0 * HF, NNIE * HF, NN);
    // hop 1
    k_spmm<<<gSpmm, 256, 0, stream>>>(h, za, off, es, dinv, NN);
    gemm128<<<gGemm, 256, 0, stream>>>(za, Wt_ind + 1 * HF * HF, b_ind + HF,
                                       g_ind + HF, be_ind + HF, cat + 1 * HF,
                                       NNIE * HF, NN);
    // hop 2
    k_spmm<<<gSpmm, 256, 0, stream>>>(za, zb, off, es, dinv, NN);
    gemm128<<<gGemm, 256, 0, stream>>>(zb, Wt_ind + 2 * HF * HF,
                                       b_ind + 2 * HF, g_ind + 2 * HF,
                                       be_ind + 2 * HF, cat + 2 * HF,
                                       NNIE * HF, NN);
    // hop 3
    k_spmm<<<gSpmm, 256, 0, stream>>>(zb, za, off, es, dinv, NN);
    gemm128<<<gGemm, 256, 0, stream>>>(za, Wt_ind + 3 * HF * HF,
                                       b_ind + 3 * HF, g_ind + 3 * HF,
                                       be_ind + 3 * HF, cat + 3 * HF,
                                       NNIE * HF, NN);
    // relation network
    gemm_mfma<NNIE * HF, false, unsigned short, float>
        <<<gGemm, 256, 0, stream>>>(cat, NNIE * HF, Wt_rel, b_rel, g_rel,
                                    be_rel, out, HF, NN);
}

// Round 6
// 765.405 us; speedup vs baseline: 2.1631x; 1.0337x over previous
//
#include <hip/hip_runtime.h>
#include <hip/hip_bf16.h>

// Problem constants (match reference)
#define NN 100000      // nodes
#define FE 512         // in_feats
#define HF 128         // h_feats
#define NE 1600000     // edges
#define NNIE 4         // hops+1

typedef __attribute__((ext_vector_type(8))) __bf16 bf16x8;
typedef __attribute__((ext_vector_type(4))) float f32x4;
typedef __attribute__((ext_vector_type(8))) unsigned short ushort8;

__device__ __forceinline__ unsigned short f2bf(float f) {
    unsigned u = __float_as_uint(f);
    unsigned r = (u + 0x7fffu + ((u >> 16) & 1u)) >> 16;  // RNE
    return (unsigned short)r;
}
__device__ __forceinline__ float b2f(unsigned short u) {
    return __uint_as_float(((unsigned)u) << 16);
}

// ---------------------------------------------------------------------------
// Graph preprocessing
// ---------------------------------------------------------------------------
__global__ __launch_bounds__(256) void k_zero(int* __restrict__ deg,
                                              int* __restrict__ cursor, int n) {
    int i = blockIdx.x * 256 + threadIdx.x;
    if (i < n) { deg[i] = 0; cursor[i] = 0; }
}

__global__ __launch_bounds__(256) void k_count(const int* __restrict__ row,
                                               int* __restrict__ deg, int e) {
    int i = blockIdx.x * 256 + threadIdx.x;
    if (i < e) atomicAdd(&deg[row[i]], 1);
}

// ---- multi-block exclusive scan (3 passes); pass 1 also computes dinv -----
__global__ __launch_bounds__(1024) void k_scan1(const int* __restrict__ cnt,
                                                int* __restrict__ off,
                                                int* __restrict__ bsum,
                                                float* __restrict__ dinv,
                                                int n) {
    __shared__ int wsum[16];
    const int tid = threadIdx.x, lane = tid & 63, wid = tid >> 6;
    const int i = blockIdx.x * 1024 + tid;
    const int v = (i < n) ? cnt[i] : 0;
    if (i < n) dinv[i] = rsqrtf((float)(v + 1));  // +1 self loop
    int x = v;
#pragma unroll
    for (int s = 1; s < 64; s <<= 1) {
        int t = __shfl_up(x, s);
        if (lane >= s) x += t;
    }
    if (lane == 63) wsum[wid] = x;
    __syncthreads();
    if (wid == 0 && lane < 16) {
        int t = wsum[lane];
#pragma unroll
        for (int s = 1; s < 16; s <<= 1) {
            int u = __shfl_up(t, s);
            if (lane >= s) t += u;
        }
        wsum[lane] = t;
    }
    __syncthreads();
    const int wexc = (wid == 0) ? 0 : wsum[wid - 1];
    if (i < n) off[i] = wexc + x - v;  // block-local exclusive
    if (tid == 0) bsum[blockIdx.x] = wsum[15];
}
__global__ __launch_bounds__(1024) void k_scan2(int* __restrict__ bsum, int nb,
                                                int* __restrict__ total_out) {
    __shared__ int wsum[16];
    const int tid = threadIdx.x, lane = tid & 63, wid = tid >> 6;
    const int v = (tid < nb) ? bsum[tid] : 0;
    int x = v;
#pragma unroll
    for (int s = 1; s < 64; s <<= 1) {
        int t = __shfl_up(x, s);
        if (lane >= s) x += t;
    }
    if (lane == 63) wsum[wid] = x;
    __syncthreads();
    if (wid == 0 && lane < 16) {
        int t = wsum[lane];
#pragma unroll
        for (int s = 1; s < 16; s <<= 1) {
            int u = __shfl_up(t, s);
            if (lane >= s) t += u;
        }
        wsum[lane] = t;
    }
    __syncthreads();
    const int wexc = (wid == 0) ? 0 : wsum[wid - 1];
    if (tid < nb) bsum[tid] = wexc + x - v;
    if (tid == 0) *total_out = wsum[15];
}
__global__ __launch_bounds__(256) void k_scan3(int* __restrict__ off,
                                               const int* __restrict__ bsum,
                                               int n) {
    int i = blockIdx.x * 256 + threadIdx.x;
    if (i < n) off[i] += bsum[i >> 10];
}

// fill interleaved (col, weight) edge records
__global__ __launch_bounds__(256) void k_fill(const int* __restrict__ rows,
                                              const int* __restrict__ cols,
                                              const float* __restrict__ dinv,
                                              const int* __restrict__ off,
                                              int* __restrict__ cursor,
                                              int2* __restrict__ es, int e) {
    int i = blockIdx.x * 256 + threadIdx.x;
    if (i < e) {
        int r = rows[i], c = cols[i];
        int pos = off[r] + atomicAdd(&cursor[r], 1);
        es[pos] = make_int2(c, __float_as_int(dinv[r] * dinv[c]));
    }
}

// all weight transposes+cvt in one launch (n-major B^T layouts)
__global__ __launch_bounds__(256) void k_wt_all(
    const float* __restrict__ Wu, const float* __restrict__ Wr,
    const float* __restrict__ Wi, unsigned short* __restrict__ Tu,
    unsigned short* __restrict__ Tr, unsigned short* __restrict__ Ti) {
    int i = blockIdx.x * 256 + threadIdx.x;
    if (i < 65536) {
        int k = i >> 7, n = i & 127;
        Tu[n * 512 + k] = f2bf(Wu[i]);
    } else if (i < 131072) {
        int j = i - 65536;
        int k = j >> 7, n = j & 127;
        Tr[n * 512 + k] = f2bf(Wr[j]);
    } else if (i < 196608) {
        int j = i - 131072;
        int hh = j >> 14, r = j & 16383;
        int k = r >> 7, n = r & 127;
        Ti[hh * 16384 + n * 128 + k] = f2bf(Wi[j]);
    }
}

// ---------------------------------------------------------------------------
// SpMM (bf16): y[i] = dinv[i]^2*z[i] + sum_e w_e * z[col_e]
// Wave = 4 edge-groups x 16 feature-lanes; 16B gathers, 4-deep unroll.
// ---------------------------------------------------------------------------
__global__ __launch_bounds__(256) void k_spmm(
    const unsigned short* __restrict__ z, unsigned short* __restrict__ y,
    const int* __restrict__ off, const int2* __restrict__ es,
    const float* __restrict__ dinv, int n) {
    const int node = blockIdx.x * 4 + (threadIdx.x >> 6);
    if (node >= n) return;
    const int lane = threadIdx.x & 63;
    const int g = lane >> 4;  // edge slot 0..3
    const int l = lane & 15;  // feature slice (8 feats)

    float acc[8];
#pragma unroll
    for (int j = 0; j < 8; j++) acc[j] = 0.0f;

    const int p0 = off[node], p1 = off[node + 1];
    int p = p0 + g;
    for (; p + 12 < p1; p += 16) {  // 4 edges per group in flight
        const int2 e0 = es[p], e1 = es[p + 4], e2 = es[p + 8], e3 = es[p + 12];
        const ushort8 t0 = *(const ushort8*)(z + (size_t)e0.x * HF + 8 * l);
        const ushort8 t1 = *(const ushort8*)(z + (size_t)e1.x * HF + 8 * l);
        const ushort8 t2 = *(const ushort8*)(z + (size_t)e2.x * HF + 8 * l);
        const ushort8 t3 = *(const ushort8*)(z + (size_t)e3.x * HF + 8 * l);
        const float w0 = __int_as_float(e0.y), w1 = __int_as_float(e1.y);
        const float w2 = __int_as_float(e2.y), w3 = __int_as_float(e3.y);
#pragma unroll
        for (int j = 0; j < 8; j++) acc[j] = fmaf(w0, b2f(t0[j]), acc[j]);
#pragma unroll
        for (int j = 0; j < 8; j++) acc[j] = fmaf(w1, b2f(t1[j]), acc[j]);
#pragma unroll
        for (int j = 0; j < 8; j++) acc[j] = fmaf(w2, b2f(t2[j]), acc[j]);
#pragma unroll
        for (int j = 0; j < 8; j++) acc[j] = fmaf(w3, b2f(t3[j]), acc[j]);
    }
    for (; p + 4 < p1; p += 8) {
        const int2 e0 = es[p], e1 = es[p + 4];
        const ushort8 t0 = *(const ushort8*)(z + (size_t)e0.x * HF + 8 * l);
        const ushort8 t1 = *(const ushort8*)(z + (size_t)e1.x * HF + 8 * l);
        const float w0 = __int_as_float(e0.y), w1 = __int_as_float(e1.y);
#pragma unroll
        for (int j = 0; j < 8; j++) acc[j] = fmaf(w0, b2f(t0[j]), acc[j]);
#pragma unroll
        for (int j = 0; j < 8; j++) acc[j] = fmaf(w1, b2f(t1[j]), acc[j]);
    }
    if (p < p1) {
        const int2 e0 = es[p];
        const ushort8 t0 = *(const ushort8*)(z + (size_t)e0.x * HF + 8 * l);
        const float w0 = __int_as_float(e0.y);
#pragma unroll
        for (int j = 0; j < 8; j++) acc[j] = fmaf(w0, b2f(t0[j]), acc[j]);
    }
    if (g == 0) {  // self loop
        const float di = dinv[node];
        const ushort8 v = *(const ushort8*)(z + (size_t)node * HF + 8 * l);
        const float d2 = di * di;
#pragma unroll
        for (int j = 0; j < 8; j++) acc[j] = fmaf(d2, b2f(v[j]), acc[j]);
    }
#pragma unroll
    for (int j = 0; j < 8; j++) {
        acc[j] += __shfl_xor(acc[j], 16);
        acc[j] += __shfl_xor(acc[j], 32);
    }
    if (g == 0) {
        ushort8 o;
#pragma unroll
        for (int j = 0; j < 8; j++) o[j] = f2bf(acc[j]);
        *(ushort8*)(y + (size_t)node * HF + 8 * l) = o;
    }
}

// ---------------------------------------------------------------------------
// Unified-transform GEMM (M x 512 @ 512 x 128, fp32 A) + row-L2-normalize of
// A (epilogue scale) + bias + LayerNorm + ReLU -> bf16 out.
// ---------------------------------------------------------------------------
__global__ __launch_bounds__(256) void gemm_uni(
    const float* __restrict__ A, const unsigned short* __restrict__ Wt,
    const float* __restrict__ bias, const float* __restrict__ g,
    const float* __restrict__ be, unsigned short* __restrict__ out, int M) {
    constexpr int K = FE;
    constexpr int LDT = 72;  // 64 + 8 pad shorts
    __shared__ unsigned short Ast[64][LDT];
    __shared__ unsigned short Bst[128][LDT];
    __shared__ float rn_s[64];

    const int tid = threadIdx.x;
    const int row0 = blockIdx.x * 64;
    const int w = tid >> 6;
    const int lane = tid & 63;
    const int m = lane & 15;
    const int q = lane >> 4;
    const int lrow = tid >> 2;
    const int lq = tid & 3;

    f32x4 acc[8];
#pragma unroll
    for (int t = 0; t < 8; t++) acc[t] = (f32x4){0.f, 0.f, 0.f, 0.f};

    float sumsq = 0.0f;
    const bool arow_ok = (row0 + lrow) < M;

    for (int k0 = 0; k0 < K; k0 += 64) {
        __syncthreads();
#pragma unroll
        for (int oo = 0; oo < 2; oo++) {
            const int o = lq + 4 * oo;
            f32x4 a0 = (f32x4){0.f, 0.f, 0.f, 0.f}, a1 = a0;
            if (arow_ok) {
                const float* Ap =
                    A + (size_t)(row0 + lrow) * K + k0 + 8 * o;
                a0 = *(const f32x4*)Ap;
                a1 = *(const f32x4*)(Ap + 4);
            }
#pragma unroll
            for (int j = 0; j < 4; j++) sumsq += a0[j] * a0[j] + a1[j] * a1[j];
            ushort8 pk;
#pragma unroll
            for (int j = 0; j < 4; j++) {
                pk[j] = f2bf(a0[j]);
                pk[j + 4] = f2bf(a1[j]);
            }
            *(ushort8*)&Ast[lrow][8 * o] = pk;
        }
        const int bn = tid >> 1;
#pragma unroll
        for (int kk = 0; kk < 4; kk++) {
            const int o = (tid & 1) + 2 * kk;
            *(ushort8*)&Bst[bn][8 * o] =
                *(const ushort8*)(Wt + (size_t)bn * K + k0 + 8 * o);
        }
        __syncthreads();
#pragma unroll
        for (int jj = 0; jj < 2; jj++) {
            bf16x8 af = *(const bf16x8*)&Ast[16 * w + m][8 * q + 32 * jj];
#pragma unroll
            for (int t = 0; t < 8; t++) {
                bf16x8 bfv = *(const bf16x8*)&Bst[16 * t + m][8 * q + 32 * jj];
                acc[t] = __builtin_amdgcn_mfma_f32_16x16x32_bf16(af, bfv,
                                                                 acc[t], 0, 0,
                                                                 0);
            }
        }
    }

    sumsq += __shfl_xor(sumsq, 1);
    sumsq += __shfl_xor(sumsq, 2);
    if (lq == 0) rn_s[lrow] = 1.0f / fmaxf(sqrtf(sumsq), 1e-12f);
    __syncthreads();

    float bb[8], gg[8], ee[8];
#pragma unroll
    for (int t = 0; t < 8; t++) {
        bb[t] = bias[16 * t + m];
        gg[t] = g[16 * t + m];
        ee[t] = be[16 * t + m];
    }
#pragma unroll
    for (int r = 0; r < 4; r++) {
        const int lrow2 = 16 * w + 4 * q + r;
        const float rn = rn_s[lrow2];
        float s1 = 0.f, s2 = 0.f;
#pragma unroll
        for (int t = 0; t < 8; t++) {
            float y = fmaf(acc[t][r], rn, bb[t]);
            s1 += y;
            s2 = fmaf(y, y, s2);
        }
#pragma unroll
        for (int mask = 1; mask <= 8; mask <<= 1) {
            s1 += __shfl_xor(s1, mask);
            s2 += __shfl_xor(s2, mask);
        }
        const float mean = s1 * (1.0f / 128.0f);
        const float var = fmaxf(s2 * (1.0f / 128.0f) - mean * mean, 0.0f);
        const float rstd = rsqrtf(var + 1e-5f);
        const int grow = row0 + lrow2;
        if (grow < M) {
#pragma unroll
            for (int t = 0; t < 8; t++) {
                float y = fmaf(acc[t][r], rn, bb[t]);
                float o = fmaxf(fmaf((y - mean) * rstd, gg[t], ee[t]), 0.0f);
                out[(size_t)grow * HF + 16 * t + m] = f2bf(o);
            }
        }
    }
}

// ---------------------------------------------------------------------------
// Fused tail: for each hop i, ns_i = relu(LN(z_i @ W_ind_i + b_i)) computed
// in-register (A-frags direct from global), transposed through LDS, and
// immediately folded into the rel GEMM partial: acc2 += ns_i @ W_rel[:,k_i].
// Never materializes cat. Final epilogue: relu(LN(. + b_rel)) -> fp32 out.
// Weight staging: 128 rows x 128 shorts = 16 octets/row, 2 threads/row ->
// 8 octets per thread (k=0..7, o=(tid&1)+2k in 0..15).  [R5 bug: was k<4]
// ---------------------------------------------------------------------------
__global__ __launch_bounds__(256) void k_tail(
    const unsigned short* __restrict__ z0, const unsigned short* __restrict__ z1,
    const unsigned short* __restrict__ z2, const unsigned short* __restrict__ z3,
    const unsigned short* __restrict__ Wt_ind,  // [4][128][128] n-major
    const float* __restrict__ b_ind, const float* __restrict__ g_ind,
    const float* __restrict__ be_ind,
    const unsigned short* __restrict__ Wt_rel,  // [128][512] n-major
    const float* __restrict__ b_rel, const float* __restrict__ g_rel,
    const float* __restrict__ be_rel, float* __restrict__ out, int M) {
    constexpr int LDW = 136;  // 128 + 8 pad shorts
    __shared__ unsigned short Wst[128][LDW];
    __shared__ unsigned short nsT[64][LDW];

    const int tid = threadIdx.x;
    const int row0 = blockIdx.x * 64;
    const int w = tid >> 6;
    const int lane = tid & 63;
    const int m = lane & 15;
    const int q = lane >> 4;
    const int bn = tid >> 1;

    const unsigned short* zs[4] = {z0, z1, z2, z3};

    f32x4 acc2[8];
#pragma unroll
    for (int t = 0; t < 8; t++) acc2[t] = (f32x4){0.f, 0.f, 0.f, 0.f};

    int arow = row0 + 16 * w + m;  // this lane's A-fragment row (clamped)
    if (arow >= M) arow = M - 1;

#pragma unroll
    for (int hop = 0; hop < NNIE; hop++) {
        __syncthreads();
        // ---- stage W_ind[hop] (B^T, 128x128): 8 octets per thread
        const unsigned short* Wi = Wt_ind + hop * HF * HF;
#pragma unroll
        for (int k = 0; k < 8; k++) {
            const int o = (tid & 1) + 2 * k;
            *(ushort8*)&Wst[bn][8 * o] =
                *(const ushort8*)(Wi + (size_t)bn * HF + 8 * o);
        }
        __syncthreads();
        // ---- MLP GEMM: A direct from global z_hop
        f32x4 acc[8];
#pragma unroll
        for (int t = 0; t < 8; t++) acc[t] = (f32x4){0.f, 0.f, 0.f, 0.f};
        const unsigned short* zp = zs[hop] + (size_t)arow * HF;
#pragma unroll
        for (int jj = 0; jj < 4; jj++) {
            bf16x8 af = *(const bf16x8*)(zp + 8 * q + 32 * jj);
#pragma unroll
            for (int t = 0; t < 8; t++) {
                bf16x8 bfv = *(const bf16x8*)&Wst[16 * t + m][8 * q + 32 * jj];
                acc[t] = __builtin_amdgcn_mfma_f32_16x16x32_bf16(af, bfv,
                                                                 acc[t], 0, 0,
                                                                 0);
            }
        }
        // ---- LN + ReLU epilogue -> nsT (bf16, C-layout -> row-major tile)
        float bb[8], gg[8], ee[8];
#pragma unroll
        for (int t = 0; t < 8; t++) {
            bb[t] = b_ind[hop * HF + 16 * t + m];
            gg[t] = g_ind[hop * HF + 16 * t + m];
            ee[t] = be_ind[hop * HF + 16 * t + m];
        }
#pragma unroll
        for (int r = 0; r < 4; r++) {
            const int lrow2 = 16 * w + 4 * q + r;
            float s1 = 0.f, s2 = 0.f;
#pragma unroll
            for (int t = 0; t < 8; t++) {
                float y = acc[t][r] + bb[t];
                s1 += y;
                s2 = fmaf(y, y, s2);
            }
#pragma unroll
            for (int mask = 1; mask <= 8; mask <<= 1) {
                s1 += __shfl_xor(s1, mask);
                s2 += __shfl_xor(s2, mask);
            }
            const float mean = s1 * (1.0f / 128.0f);
            const float var = fmaxf(s2 * (1.0f / 128.0f) - mean * mean, 0.0f);
            const float rstd = rsqrtf(var + 1e-5f);
#pragma unroll
            for (int t = 0; t < 8; t++) {
                float y = acc[t][r] + bb[t];
                float o = fmaxf(fmaf((y - mean) * rstd, gg[t], ee[t]), 0.0f);
                nsT[lrow2][16 * t + m] = f2bf(o);
            }
        }
        __syncthreads();  // nsT visible; Wst free for rel chunk
        // ---- stage W_rel k-chunk hop (B^T rows, k = 128*hop..+127)
#pragma unroll
        for (int k = 0; k < 8; k++) {
            const int o = (tid & 1) + 2 * k;
            *(ushort8*)&Wst[bn][8 * o] =
                *(const ushort8*)(Wt_rel + (size_t)bn * (NNIE * HF) +
                                  HF * hop + 8 * o);
        }
        __syncthreads();
        // ---- rel partial GEMM: A from nsT, accumulate acc2
#pragma unroll
        for (int jj = 0; jj < 4; jj++) {
            bf16x8 af = *(const bf16x8*)&nsT[16 * w + m][8 * q + 32 * jj];
#pragma unroll
            for (int t = 0; t < 8; t++) {
                bf16x8 bfv = *(const bf16x8*)&Wst[16 * t + m][8 * q + 32 * jj];
                acc2[t] = __builtin_amdgcn_mfma_f32_16x16x32_bf16(af, bfv,
                                                                  acc2[t], 0,
                                                                  0, 0);
            }
        }
    }

    // ---- final epilogue: bias + LN + ReLU -> fp32 out
    float bb[8], gg[8], ee[8];
#pragma unroll
    for (int t = 0; t < 8; t++) {
        bb[t] = b_rel[16 * t + m];
        gg[t] = g_rel[16 * t + m];
        ee[t] = be_rel[16 * t + m];
    }
#pragma unroll
    for (int r = 0; r < 4; r++) {
        const int lrow2 = 16 * w + 4 * q + r;
        float s1 = 0.f, s2 = 0.f;
#pragma unroll
        for (int t = 0; t < 8; t++) {
            float y = acc2[t][r] + bb[t];
            s1 += y;
            s2 = fmaf(y, y, s2);
        }
#pragma unroll
        for (int mask = 1; mask <= 8; mask <<= 1) {
            s1 += __shfl_xor(s1, mask);
            s2 += __shfl_xor(s2, mask);
        }
        const float mean = s1 * (1.0f / 128.0f);
        const float var = fmaxf(s2 * (1.0f / 128.0f) - mean * mean, 0.0f);
        const float rstd = rsqrtf(var + 1e-5f);
        const int grow = row0 + lrow2;
        if (grow < M) {
#pragma unroll
            for (int t = 0; t < 8; t++) {
                float y = acc2[t][r] + bb[t];
                float o = fmaxf(fmaf((y - mean) * rstd, gg[t], ee[t]), 0.0f);
                out[(size_t)grow * HF + 16 * t + m] = o;
            }
        }
    }
}

// ---------------------------------------------------------------------------
extern "C" void kernel_launch(void* const* d_in, const int* in_sizes, int n_in,
                              void* d_out, int out_size, void* d_ws,
                              size_t ws_size, hipStream_t stream) {
    const int* ei = (const int*)d_in[0];          // [2, E]
    const float* feats = (const float*)d_in[1];   // [N, 512]
    const float* W_uni = (const float*)d_in[2];   // [512,128]
    const float* b_uni = (const float*)d_in[3];
    const float* g_uni = (const float*)d_in[4];
    const float* be_uni = (const float*)d_in[5];
    const float* W_ind = (const float*)d_in[6];   // [4,128,128]
    const float* b_ind = (const float*)d_in[7];
    const float* g_ind = (const float*)d_in[8];
    const float* be_ind = (const float*)d_in[9];
    const float* W_rel = (const float*)d_in[10];  // [512,128]
    const float* b_rel = (const float*)d_in[11];
    const float* g_rel = (const float*)d_in[12];
    const float* be_rel = (const float*)d_in[13];
    float* out = (float*)d_out;

    char* p = (char*)d_ws;
    auto alloc = [&](size_t bytes) {
        void* r = (void*)p;
        p += (bytes + 255) & ~(size_t)255;
        return r;
    };
    int* deg = (int*)alloc(NN * 4);
    int* cursor = (int*)alloc(NN * 4);
    int* off = (int*)alloc((NN + 1) * 4);
    int* bsum = (int*)alloc(1024 * 4);
    int2* es = (int2*)alloc((size_t)NE * 8);
    float* dinv = (float*)alloc(NN * 4);
    unsigned short* Wt_uni = (unsigned short*)alloc(128 * FE * 2);
    unsigned short* Wt_rel = (unsigned short*)alloc(128 * (NNIE * HF) * 2);
    unsigned short* Wt_ind = (unsigned short*)alloc(NNIE * HF * HF * 2);
    unsigned short* h = (unsigned short*)alloc((size_t)NN * HF * 2);
    unsigned short* za = (unsigned short*)alloc((size_t)NN * HF * 2);
    unsigned short* zb = (unsigned short*)alloc((size_t)NN * HF * 2);
    unsigned short* zc = (unsigned short*)alloc((size_t)NN * HF * 2);

    const int gE = (NE + 255) / 256;
    const int gN = (NN + 255) / 256;
    const int gGemm = (NN + 63) / 64;
    const int gSpmm = (NN + 3) / 4;
    const int nbScan = (NN + 1023) / 1024;
    const int* erow = ei;
    const int* ecol = ei + NE;

    // graph prep
    k_zero<<<gN, 256, 0, stream>>>(deg, cursor, NN);
    k_count<<<gE, 256, 0, stream>>>(erow, deg, NE);
    k_scan1<<<nbScan, 1024, 0, stream>>>(deg, off, bsum, dinv, NN);
    k_scan2<<<1, 1024, 0, stream>>>(bsum, nbScan, off + NN);
    k_scan3<<<gN, 256, 0, stream>>>(off, bsum, NN);
    k_fill<<<gE, 256, 0, stream>>>(erow, ecol, dinv, off, cursor, es, NE);

    // weight transpose+cvt
    k_wt_all<<<(196608 + 255) / 256, 256, 0, stream>>>(W_uni, W_rel, W_ind,
                                                       Wt_uni, Wt_rel, Wt_ind);

    // unified transform: h = relu(LN(normalize(x) @ W_uni + b))
    gemm_uni<<<gGemm, 256, 0, stream>>>(feats, Wt_uni, b_uni, g_uni, be_uni, h,
                                        NN);
    // hops
    k_spmm<<<gSpmm, 256, 0, stream>>>(h, za, off, es, dinv, NN);
    k_spmm<<<gSpmm, 256, 0, stream>>>(za, zb, off, es, dinv, NN);
    k_spmm<<<gSpmm, 256, 0, stream>>>(zb, zc, off, es, dinv, NN);

    // fused 4x MLP + relation network
    k_tail<<<gGemm, 256, 0, stream>>>(h, za, zb, zc, Wt_ind, b_ind, g_ind,
                                      be_ind, Wt_rel, b_rel, g_rel, be_rel,
                                      out, NN);
}